// Round 4
// baseline (1977.047 us; speedup 1.0000x reference)
//
#include <hip/hip_runtime.h>
#include <hip/hip_bf16.h>
#include <stdint.h>

typedef short bf16x8 __attribute__((ext_vector_type(8)));
typedef float f32x4 __attribute__((ext_vector_type(4)));

__device__ __forceinline__ float b2f(ushort u){ return __uint_as_float(((uint32_t)u)<<16); }
__device__ __forceinline__ ushort f2b(float f){
  uint32_t u = __float_as_uint(f);
  u += 0x7fffu + ((u>>16)&1u);
  return (ushort)(u>>16);
}
__device__ __forceinline__ float hswish(float x){ return x*fminf(fmaxf(x+3.f,0.f),6.f)*(1.f/6.f); }

// async global->LDS 16B (dest = wave-uniform base + lane*16)
__device__ __forceinline__ void gll16(const void* g, void* l){
  __builtin_amdgcn_global_load_lds((const __attribute__((address_space(1))) void*)g,
                                   (__attribute__((address_space(3))) void*)l, 16, 0, 0);
}

// ---------- zero scratch accumulators ----------
__global__ void zero_f32(float* __restrict__ p, int n){
  int i = blockIdx.x*256 + threadIdx.x;
  if (i < n) p[i] = 0.f;
}

// ---------- f32 -> bf16 ----------
__global__ void cvt_bf16(const float* __restrict__ in, ushort* __restrict__ out, int n){
  int i = blockIdx.x*256 + threadIdx.x;
  if (i < n) out[i] = f2b(in[i]);
}

// ---------- transpose im_emd (B,C,N) f32 -> At[(b*N+n)][c] bf16 ----------
__global__ __launch_bounds__(256) void transpose_kernel(const float* __restrict__ im, ushort* __restrict__ At){
  __shared__ ushort t[64][65];
  const int b = blockIdx.z;
  const int c0 = blockIdx.y*64, n0 = blockIdx.x*64;
  const int tx = threadIdx.x & 63, ty = threadIdx.x >> 6;
  #pragma unroll
  for (int i=0;i<16;++i){
    int c = ty + i*4;
    t[c][tx] = f2b(im[((size_t)(b*1024 + c0+c))*9216 + n0 + tx]);
  }
  __syncthreads();
  const int cx = threadIdx.x & 31, ny = threadIdx.x >> 5;
  #pragma unroll
  for (int j=0;j<8;++j){
    int n = ny + j*8;
    uint32_t u = (uint32_t)t[cx*2][n] | ((uint32_t)t[cx*2+1][n] << 16);
    *(uint32_t*)&At[((size_t)(b*9216 + n0+n))*1024 + c0 + cx*2] = u;
  }
}

// ---------- MFMA GEMM: C[m][n] = sum_k A[m*K+k]*B[n*K+k]  (bf16, async staging, XOR-swizzled LDS) ----------
// grid = (N/128, M/128): n-tiles fastest so blocks sharing an A m-tile are temporally adjacent.
__global__ __launch_bounds__(256) void gemm_bt(
    const ushort* __restrict__ A, const ushort* __restrict__ Bm,
    ushort* __restrict__ Cm, int M, int N, int K)
{
  __shared__ __align__(16) ushort As[128*64];
  __shared__ __align__(16) ushort Bs[128*64];
  const int tid = threadIdx.x;
  const int l = tid & 63;
  const int w = tid >> 6;
  const int wm = w >> 1, wn = w & 1;
  const size_t n0 = (size_t)blockIdx.x * 128;
  const size_t m0 = (size_t)blockIdx.y * 128;
  const int lr = l & 15, lk = l >> 4;
  const int wbase = tid & ~63;   // wave-uniform

  f32x4 acc[4][4];
  #pragma unroll
  for (int i=0;i<4;++i)
    #pragma unroll
    for (int j=0;j<4;++j) acc[i][j] = (f32x4){0.f,0.f,0.f,0.f};

  for (int kt = 0; kt < K; kt += 64) {
    #pragma unroll
    for (int it=0; it<4; ++it) {
      int idx = it*256 + tid;
      int row = idx >> 3, c8 = idx & 7;
      int sc8 = c8 ^ (row & 7);   // pre-swizzled source column (permutes within the row's 128B segment)
      gll16(&A[(m0+row)*K + kt + sc8*8], &As[(it*256 + wbase)*8]);
      gll16(&Bm[(n0+row)*K + kt + sc8*8], &Bs[(it*256 + wbase)*8]);
    }
    __syncthreads();
    #pragma unroll
    for (int kk=0; kk<64; kk+=32) {
      bf16x8 af[4], bfr[4];
      #pragma unroll
      for (int i=0;i<4;++i){
        int row = wm*64 + i*16 + lr;
        af[i] = *(const bf16x8*)&As[row*64 + ((kk + lk*8) ^ ((row&7)<<3))];
      }
      #pragma unroll
      for (int j=0;j<4;++j){
        int row = wn*64 + j*16 + lr;
        bfr[j] = *(const bf16x8*)&Bs[row*64 + ((kk + lk*8) ^ ((row&7)<<3))];
      }
      #pragma unroll
      for (int i=0;i<4;++i)
        #pragma unroll
        for (int j=0;j<4;++j)
          acc[i][j] = __builtin_amdgcn_mfma_f32_16x16x32_bf16(af[i], bfr[j], acc[i][j], 0, 0, 0);
    }
    __syncthreads();
  }
  #pragma unroll
  for (int i=0;i<4;++i)
    #pragma unroll
    for (int j=0;j<4;++j)
      #pragma unroll
      for (int r=0;r<4;++r) {
        size_t row = m0 + wm*64 + i*16 + lk*4 + r;
        size_t col = n0 + wn*64 + j*16 + lr;
        Cm[row*N + col] = f2b(acc[i][j][r]);
      }
}

// ---------- column stats (sum, sumsq); blockDim = C/8, grid-stride rows ----------
__global__ void col_stats_v(const ushort* __restrict__ X, float* __restrict__ sums,
                            float* __restrict__ sqs, int C, int nrows)
{
  const int tid = threadIdx.x;
  float s[8] = {0,0,0,0,0,0,0,0};
  float q[8] = {0,0,0,0,0,0,0,0};
  const ushort* base = X + (size_t)tid*8;
  for (int r = blockIdx.x; r < nrows; r += gridDim.x){
    uint4 u = *(const uint4*)(base + (size_t)r*C);
    const ushort* ub = (const ushort*)&u;
    #pragma unroll
    for (int e=0;e<8;++e){ float v=b2f(ub[e]); s[e]+=v; q[e]+=v*v; }
  }
  #pragma unroll
  for (int e=0;e<8;++e){
    atomicAdd(&sums[tid*8+e], s[e]);
    atomicAdd(&sqs [tid*8+e], q[e]);
  }
}

__global__ void bn_finalize(const float* __restrict__ sums, const float* __restrict__ sqs,
                            const float* __restrict__ g, const float* __restrict__ bb,
                            float* __restrict__ scale, float* __restrict__ shift, int C, float invn)
{
  int c = blockIdx.x*256 + threadIdx.x;
  if (c < C){
    float mu = sums[c]*invn;
    float var = sqs[c]*invn - mu*mu;
    float k = g[c] * rsqrtf(var + 1e-5f);
    scale[c] = k;
    shift[c] = bb[c] - mu*k;
  }
}

// ---------- BN + hardswish in place on y1 ----------
__global__ __launch_bounds__(256) void bn_hswish(ushort* __restrict__ y, const float* __restrict__ scale, const float* __restrict__ shift)
{
  __shared__ float sc[512], sh[512];
  for (int i=threadIdx.x;i<512;i+=256){ sc[i]=scale[i]; sh[i]=shift[i]; }
  __syncthreads();
  const size_t total = (size_t)73728*512/8;
  for (size_t idx = (size_t)blockIdx.x*256+threadIdx.x; idx < total; idx += (size_t)gridDim.x*256){
    uint4 u = *(uint4*)&y[idx*8];
    ushort* up = (ushort*)&u;
    int c0 = ((int)(idx & 63))*8;
    #pragma unroll
    for (int e=0;e<8;++e){
      float x = b2f(up[e])*sc[c0+e] + sh[c0+e];
      up[e] = f2b(hswish(x));
    }
    *(uint4*)&y[idx*8] = u;
  }
}

// ---------- q = text @ Wq^T (raw, f32) ----------
__global__ __launch_bounds__(256) void q_gemm(const float* __restrict__ text, const float* __restrict__ Wq, float* __restrict__ qraw)
{
  __shared__ __align__(16) float xr[512];
  const int t = blockIdx.x, tid = threadIdx.x;
  for (int i=tid;i<512;i+=256) xr[i] = text[t*512+i];
  __syncthreads();
  #pragma unroll
  for (int cj=0;cj<2;++cj){
    int c = cj*256+tid;
    const float4* wp = (const float4*)(Wq + (size_t)c*512);
    const float4* xp = (const float4*)xr;
    float a=0.f;
    for (int u=0;u<128;++u){
      float4 wv = wp[u], xv = xp[u];
      a += wv.x*xv.x + wv.y*xv.y + wv.z*xv.z + wv.w*xv.w;
    }
    qraw[t*512+c]=a;
  }
}

// ---------- q BN + fold K-BN scale into Qh (bf16), cQ[t,h] = 0.125*dot(q_bn, tk) ----------
__global__ __launch_bounds__(512) void q_bn_qh(const float* __restrict__ qraw, const float* __restrict__ g,
                                               const float* __restrict__ bb,
                                               const float* __restrict__ scale2, const float* __restrict__ shift2,
                                               ushort* __restrict__ Qh, float* __restrict__ cQ)
{
  const int c = threadIdx.x;
  const int h = c >> 6, d = c & 63;
  float s=0.f,q=0.f;
  for (int t=0;t<60;++t){ float v = qraw[t*512+c]; s+=v; q+=v*v; }
  float mu=s*(1.f/60.f), var=q*(1.f/60.f)-mu*mu;
  float k = g[c]*rsqrtf(var+1e-5f);
  float sh = bb[c]-mu*k;
  const float sk = scale2[h*192+d]*0.125f;
  const float tk = shift2[h*192+d]*0.125f;
  for (int t=0;t<60;++t){
    float qv = qraw[t*512+c]*k+sh;
    Qh[(h*64+t)*64+d] = f2b(qv*sk);
    float contrib = qv*tk;
    #pragma unroll
    for (int o=32;o>0;o>>=1) contrib += __shfl_xor(contrib,o);
    if (d==0) cQ[h*64+t] = contrib;
  }
  for (int t=60;t<64;++t) Qh[(h*64+t)*64+d] = 0;
}

// ---------- scores: S[bh][t][n] = Qh . Kraw + cQ + bias  (MFMA) ----------
__global__ __launch_bounds__(256) void scores_mfma(
    const ushort* __restrict__ Qh, const float* __restrict__ cQ,
    const ushort* __restrict__ kv, const float* __restrict__ biases,
    float* __restrict__ S)
{
  __shared__ __align__(16) ushort Qs[64*72];
  __shared__ float bias_l[10000];
  const int tid = threadIdx.x;
  const int l = tid & 63, w = tid >> 6;
  const int lr = l & 15, lk = l >> 4;
  const int h = blockIdx.y, b = blockIdx.z;
  const int n0 = blockIdx.x * 256;
  const int bh = b*8 + h;
  for (int cid = tid; cid < 512; cid += 256){
    int row = cid >> 3, c8 = cid & 7;
    *(uint4*)&Qs[row*72 + c8*8] = *(const uint4*)&Qh[(size_t)(h*64 + row)*64 + c8*8];
  }
  for (int i = tid; i < 10000; i += 256) bias_l[i] = biases[h*10000 + i];
  __syncthreads();
  f32x4 acc[4][4];
  #pragma unroll
  for (int i=0;i<4;++i)
    #pragma unroll
    for (int j=0;j<4;++j) acc[i][j]=(f32x4){0.f,0.f,0.f,0.f};
  const ushort* kbase = kv + ((size_t)(b*9216 + n0 + w*64))*1536 + h*192;
  #pragma unroll
  for (int kk=0; kk<64; kk+=32){
    bf16x8 af[4], bfr[4];
    #pragma unroll
    for (int i=0;i<4;++i) af[i] = *(const bf16x8*)&Qs[(i*16+lr)*72 + kk + lk*8];
    #pragma unroll
    for (int j=0;j<4;++j) bfr[j] = *(const bf16x8*)&kbase[(size_t)(j*16+lr)*1536 + kk + lk*8];
    #pragma unroll
    for (int i=0;i<4;++i)
      #pragma unroll
      for (int j=0;j<4;++j)
        acc[i][j] = __builtin_amdgcn_mfma_f32_16x16x32_bf16(af[i], bfr[j], acc[i][j], 0,0,0);
  }
  float* Sb = S + (size_t)bh*64*9216;
  #pragma unroll
  for (int j=0;j<4;++j){
    int n = n0 + w*64 + j*16 + lr;
    int py = n/96, px = n - py*96;
    const float* brow = &bias_l[100*py];
    #pragma unroll
    for (int i=0;i<4;++i){
      #pragma unroll
      for (int r=0;r<4;++r){
        int row = i*16 + lk*4 + r;
        if (row < 60){
          int dd = row - px; dd = dd<0?-dd:dd;
          Sb[(size_t)row*9216 + n] = acc[i][j][r] + cQ[h*64+row] + brow[dd];
        }
      }
    }
  }
}

// ---------- per-row softmax stats ----------
__global__ __launch_bounds__(256) void softmax_stats(const float* __restrict__ S, float* __restrict__ rmax_, float* __restrict__ rinv_)
{
  const int t = blockIdx.x, bh = blockIdx.y, tid = threadIdx.x;
  const float4* p = (const float4*)(S + ((size_t)bh*64 + t)*9216);
  float4 vals[9];
  float m = -1e30f;
  #pragma unroll
  for (int i=0;i<9;++i){ float4 v = p[i*256+tid]; vals[i]=v; m = fmaxf(m, fmaxf(fmaxf(v.x,v.y),fmaxf(v.z,v.w))); }
  #pragma unroll
  for (int o=32;o>0;o>>=1) m = fmaxf(m, __shfl_xor(m, o));
  __shared__ float wm[4], ws[4];
  if ((tid&63)==0) wm[tid>>6]=m;
  __syncthreads();
  m = fmaxf(fmaxf(wm[0],wm[1]),fmaxf(wm[2],wm[3]));
  float ssum=0.f;
  #pragma unroll
  for (int i=0;i<9;++i){ float4 v=vals[i]; ssum += __expf(v.x-m)+__expf(v.y-m)+__expf(v.z-m)+__expf(v.w-m); }
  #pragma unroll
  for (int o=32;o>0;o>>=1) ssum += __shfl_xor(ssum,o);
  if ((tid&63)==0) ws[tid>>6]=ssum;
  __syncthreads();
  if (tid==0){ rmax_[bh*64+t]=m; rinv_[bh*64+t]=1.f/(ws[0]+ws[1]+ws[2]+ws[3]); }
}

// ---------- PV: attn_o[b][t][h*128+dv] += P @ Vraw  (MFMA, V^T staged in LDS) ----------
__global__ __launch_bounds__(256) void pv_mfma(
    const float* __restrict__ S, const ushort* __restrict__ kv,
    const float* __restrict__ rmax_, const float* __restrict__ rinv_,
    float* __restrict__ attn_out)
{
  __shared__ ushort vt[128*68];
  const int tid = threadIdx.x;
  const int l = tid & 63, w = tid >> 6;
  const int lr = l & 15, lk = l >> 4;
  const int nc = blockIdx.x, h = blockIdx.y, b = blockIdx.z;
  const int bh = b*8+h;
  const size_t Sbase = (size_t)bh*64*9216;
  float rmv[4], riv[4];
  #pragma unroll
  for (int i=0;i<4;++i){ rmv[i]=rmax_[bh*64+i*16+lr]; riv[i]=rinv_[bh*64+i*16+lr]; }
  f32x4 acc[4][2];
  #pragma unroll
  for (int i=0;i<4;++i){ acc[i][0]=(f32x4){0.f,0.f,0.f,0.f}; acc[i][1]=(f32x4){0.f,0.f,0.f,0.f}; }
  for (int ks=0; ks<576; ks+=64){
    const int n0 = nc*576 + ks;
    if (ks) __syncthreads();
    #pragma unroll
    for (int c2=0;c2<4;++c2){
      int cid = c2*256 + tid;
      int row = cid >> 4, dv0 = (cid & 15)*8;
      uint4 vv = *(const uint4*)&kv[((size_t)(b*9216 + n0 + row))*1536 + h*192 + 64 + dv0];
      const ushort* vb8 = (const ushort*)&vv;
      #pragma unroll
      for (int e=0;e<8;++e) vt[(dv0+e)*68 + row] = vb8[e];
    }
    __syncthreads();
    #pragma unroll
    for (int kk=0; kk<64; kk+=32){
      bf16x8 pa[4], vb[2];
      #pragma unroll
      for (int i=0;i<4;++i){
        const float* sp = S + Sbase + (size_t)(i*16+lr)*9216 + n0 + kk + lk*8;
        float4 s0 = *(const float4*)sp, s1 = *(const float4*)(sp+4);
        float rm=rmv[i], ri=riv[i];
        bf16x8 t_;
        t_[0]=(short)f2b(__expf(s0.x-rm)*ri);
        t_[1]=(short)f2b(__expf(s0.y-rm)*ri);
        t_[2]=(short)f2b(__expf(s0.z-rm)*ri);
        t_[3]=(short)f2b(__expf(s0.w-rm)*ri);
        t_[4]=(short)f2b(__expf(s1.x-rm)*ri);
        t_[5]=(short)f2b(__expf(s1.y-rm)*ri);
        t_[6]=(short)f2b(__expf(s1.z-rm)*ri);
        t_[7]=(short)f2b(__expf(s1.w-rm)*ri);
        pa[i]=t_;
      }
      #pragma unroll
      for (int j=0;j<2;++j){
        const ushort* vp = &vt[(w*32 + j*16 + lr)*68 + kk + lk*8];
        uint2 a0 = *(const uint2*)vp, a1 = *(const uint2*)(vp+4);
        struct PP { uint2 a,b; } pp{a0,a1};
        vb[j] = __builtin_bit_cast(bf16x8, pp);
      }
      #pragma unroll
      for (int i=0;i<4;++i){
        acc[i][0] = __builtin_amdgcn_mfma_f32_16x16x32_bf16(pa[i], vb[0], acc[i][0],0,0,0);
        acc[i][1] = __builtin_amdgcn_mfma_f32_16x16x32_bf16(pa[i], vb[1], acc[i][1],0,0,0);
      }
    }
  }
  float* ob = attn_out + (size_t)(b*60)*1024 + h*128;
  #pragma unroll
  for (int j=0;j<2;++j){
    int dv = w*32 + j*16 + lr;
    #pragma unroll
    for (int i=0;i<4;++i)
      #pragma unroll
      for (int r=0;r<4;++r){
        int row = i*16 + lk*4 + r;
        if (row < 60) atomicAdd(&ob[(size_t)row*1024 + dv], acc[i][j][r]);
      }
  }
}

// ---------- row GEMM, 8 rows/block. MODE 0: id; 2: BN direct; 3: attn-BN map. hswish if MODE>=1 ----------
template<int CIN, int COUT, int MODE>
__global__ __launch_bounds__(256) void rowgemm8(
    const float* __restrict__ X, const float* __restrict__ Wt,
    const float* __restrict__ sc, const float* __restrict__ sh,
    float* __restrict__ out)
{
  __shared__ __align__(16) float xr[8][CIN];
  const int rb0 = blockIdx.x*8, tid = threadIdx.x;
  for (int i=tid; i<8*CIN; i+=256){
    int rr = i / CIN, cc = i % CIN;
    float v = X[(size_t)(rb0+rr)*CIN + cc];
    if constexpr (MODE==2) v = v*sc[cc]+sh[cc];
    if constexpr (MODE==3){ int idx = 64 + (cc&127) + (cc>>7)*192; v = v*sc[idx]+sh[idx]; }
    if constexpr (MODE>=1) v = hswish(v);
    xr[rr][cc]=v;
  }
  __syncthreads();
  #pragma unroll
  for (int cj=0; cj<COUT/256; ++cj){
    int c = cj*256 + tid;
    const float4* wp = (const float4*)(Wt + (size_t)c*CIN);
    float a[8] = {0.f,0.f,0.f,0.f,0.f,0.f,0.f,0.f};
    for (int u=0;u<CIN/4;++u){
      float4 wv = wp[u];
      #pragma unroll
      for (int rr=0;rr<8;++rr){
        float4 xv = *(const float4*)&xr[rr][u*4];
        a[rr] += wv.x*xv.x + wv.y*xv.y + wv.z*xv.z + wv.w*xv.w;
      }
    }
    #pragma unroll
    for (int rr=0;rr<8;++rr) out[(size_t)(rb0+rr)*COUT + c] = a[rr];
  }
}

template<int C>
__global__ void stats480(const float* __restrict__ X, const float* __restrict__ g,
                         const float* __restrict__ bb, float* __restrict__ sc, float* __restrict__ sh)
{
  int c = blockIdx.x*256 + threadIdx.x;
  float s=0.f, q=0.f;
  for (int r=0;r<480;++r){ float v = X[(size_t)r*C + c]; s+=v; q+=v*v; }
  float mu = s*(1.f/480.f), var = q*(1.f/480.f)-mu*mu;
  float k = g[c] * rsqrtf(var+1e-5f);
  sc[c]=k; sh[c]=bb[c] - mu*k;
}

__global__ void make_textd(const float* __restrict__ praw, const float* __restrict__ sp, const float* __restrict__ tp,
                           const float* __restrict__ text, float* __restrict__ textd)
{
  int i = blockIdx.x*256+threadIdx.x;
  if (i < 480*512){
    int c = i & 511, rb = i >> 9, t = rb % 60;
    textd[i] = text[t*512+c] + praw[i]*sp[c]+tp[c];
  }
}

__global__ void final_out(const float* __restrict__ f2raw, const float* __restrict__ sf, const float* __restrict__ tf,
                          const float* __restrict__ textd, float* __restrict__ outp)
{
  int i = blockIdx.x*256+threadIdx.x;
  if (i < 60*512){ int c = i & 511; outp[i] = f2raw[i]*sf[c]+tf[c] + textd[i]; }
}

extern "C" void kernel_launch(void* const* d_in, const int* in_sizes, int n_in,
                              void* d_out, int out_size, void* d_ws, size_t ws_size,
                              hipStream_t stream)
{
  (void)in_sizes; (void)n_in; (void)out_size; (void)ws_size;
  const float* im    = (const float*)d_in[0];
  const float* text  = (const float*)d_in[1];
  const float* W_dc  = (const float*)d_in[2];
  const float* g_dc  = (const float*)d_in[3];
  const float* b_dc  = (const float*)d_in[4];
  const float* W_kv  = (const float*)d_in[5];
  const float* g_kv  = (const float*)d_in[6];
  const float* b_kv  = (const float*)d_in[7];
  const float* W_q   = (const float*)d_in[8];
  const float* g_q   = (const float*)d_in[9];
  const float* b_q   = (const float*)d_in[10];
  const float* W_proj= (const float*)d_in[11];
  const float* g_proj= (const float*)d_in[12];
  const float* b_proj= (const float*)d_in[13];
  const float* biases= (const float*)d_in[14];
  const float* W_f1  = (const float*)d_in[15];
  const float* g_f1  = (const float*)d_in[16];
  const float* b_f1  = (const float*)d_in[17];
  const float* W_f2  = (const float*)d_in[18];
  const float* g_f2  = (const float*)d_in[19];
  const float* b_f2  = (const float*)d_in[20];
  float* outp = (float*)d_out;

  char* p = (char*)d_ws;
  auto alloc = [&](size_t bytes)->char*{ char* r = p; p += (bytes+255)&~(size_t)255; return r; };
  // zero zone (contiguous)
  float* s1_sum = (float*)alloc(512*4);
  float* s1_sq  = (float*)alloc(512*4);
  float* s2_sum = (float*)alloc(1536*4);
  float* s2_sq  = (float*)alloc(1536*4);
  float* attn_o = (float*)alloc((size_t)480*1024*4);
  float* zero_base = s1_sum; const int zero_n = 495616;
  // rest
  float* sc1 = (float*)alloc(512*4);
  float* sh1 = (float*)alloc(512*4);
  float* sc2 = (float*)alloc(1536*4);
  float* sh2 = (float*)alloc(1536*4);
  float* qraw = (float*)alloc(60*512*4);
  ushort* Qh = (ushort*)alloc((size_t)8*64*64*2);
  float* cQ = (float*)alloc(512*4);
  float* rmaxb = (float*)alloc(4096*4);
  float* rinvb = (float*)alloc(4096*4);
  float* proj_raw = (float*)alloc((size_t)480*512*4);
  float* sp=(float*)alloc(512*4); float* tp=(float*)alloc(512*4);
  float* textd=(float*)alloc((size_t)480*512*4);
  float* sf1=(float*)alloc(1024*4); float* tf1=(float*)alloc(1024*4);
  float* f1_raw=(float*)alloc((size_t)480*1024*4);
  float* sf2=(float*)alloc(512*4); float* tf2=(float*)alloc(512*4);
  float* f2_raw=(float*)alloc((size_t)480*512*4);
  ushort* Wdc_b = (ushort*)alloc((size_t)512*1024*2);
  ushort* Wkv_b = (ushort*)alloc((size_t)1536*512*2);
  ushort* y1 = (ushort*)alloc((size_t)73728*512*2);
  ushort* kv = (ushort*)alloc((size_t)73728*1536*2);
  ushort* At = (ushort*)alloc((size_t)73728*1024*2);
  float* S = (float*)At;  // alias: At dead after gemm1; S[64bh][64][9216] f32 == At bytes exactly

  zero_f32<<<1936,256,0,stream>>>(zero_base, zero_n);
  cvt_bf16<<<2048,256,0,stream>>>(W_dc, Wdc_b, 512*1024);
  cvt_bf16<<<3072,256,0,stream>>>(W_kv, Wkv_b, 1536*512);
  transpose_kernel<<<dim3(144,16,8),256,0,stream>>>(im, At);
  gemm_bt<<<dim3(4,576),256,0,stream>>>(At, Wdc_b, y1, 73728, 512, 1024);
  col_stats_v<<<2048,64,0,stream>>>(y1, s1_sum, s1_sq, 512, 73728);
  bn_finalize<<<2,256,0,stream>>>(s1_sum, s1_sq, g_dc, b_dc, sc1, sh1, 512, 1.f/73728.f);
  bn_hswish<<<2048,256,0,stream>>>(y1, sc1, sh1);
  gemm_bt<<<dim3(12,576),256,0,stream>>>(y1, Wkv_b, kv, 73728, 1536, 512);
  col_stats_v<<<2048,192,0,stream>>>(kv, s2_sum, s2_sq, 1536, 73728);
  bn_finalize<<<6,256,0,stream>>>(s2_sum, s2_sq, g_kv, b_kv, sc2, sh2, 1536, 1.f/73728.f);
  q_gemm<<<60,256,0,stream>>>(text, W_q, qraw);
  q_bn_qh<<<1,512,0,stream>>>(qraw, g_q, b_q, sc2, sh2, Qh, cQ);
  scores_mfma<<<dim3(36,8,8),256,0,stream>>>(Qh, cQ, kv, biases, S);
  softmax_stats<<<dim3(60,64),256,0,stream>>>(S, rmaxb, rinvb);
  pv_mfma<<<dim3(16,8,8),256,0,stream>>>(S, kv, rmaxb, rinvb, attn_o);
  rowgemm8<1024,512,3><<<60,256,0,stream>>>(attn_o, W_proj, sc2, sh2, proj_raw);
  stats480<512><<<2,256,0,stream>>>(proj_raw, g_proj, b_proj, sp, tp);
  make_textd<<<960,256,0,stream>>>(proj_raw, sp, tp, text, textd);
  rowgemm8<512,1024,0><<<60,256,0,stream>>>(textd, W_f1, nullptr, nullptr, f1_raw);
  stats480<1024><<<4,256,0,stream>>>(f1_raw, g_f1, b_f1, sf1, tf1);
  rowgemm8<1024,512,2><<<60,256,0,stream>>>(f1_raw, W_f2, sf1, tf1, f2_raw);
  stats480<512><<<2,256,0,stream>>>(f2_raw, g_f2, b_f2, sf2, tf2);
  final_out<<<120,256,0,stream>>>(f2_raw, sf2, tf2, textd, outp);
}

// Round 5
// 1112.855 us; speedup vs baseline: 1.7766x; 1.7766x over previous
//
#include <hip/hip_runtime.h>
#include <hip/hip_bf16.h>
#include <stdint.h>

typedef short bf16x8 __attribute__((ext_vector_type(8)));
typedef float f32x4 __attribute__((ext_vector_type(4)));

__device__ __forceinline__ float b2f(ushort u){ return __uint_as_float(((uint32_t)u)<<16); }
__device__ __forceinline__ ushort f2b(float f){
  uint32_t u = __float_as_uint(f);
  u += 0x7fffu + ((u>>16)&1u);
  return (ushort)(u>>16);
}
__device__ __forceinline__ float hswish(float x){ return x*fminf(fmaxf(x+3.f,0.f),6.f)*(1.f/6.f); }

// async global->LDS 16B (dest = wave-uniform base + lane*16)
__device__ __forceinline__ void gll16(const void* g, void* l){
  __builtin_amdgcn_global_load_lds((const __attribute__((address_space(1))) void*)g,
                                   (__attribute__((address_space(3))) void*)l, 16, 0, 0);
}

// ---------- zero scratch accumulators ----------
__global__ void zero_f32(float* __restrict__ p, int n){
  int i = blockIdx.x*256 + threadIdx.x;
  if (i < n) p[i] = 0.f;
}

// ---------- f32 -> bf16 ----------
__global__ void cvt_bf16(const float* __restrict__ in, ushort* __restrict__ out, int n){
  int i = blockIdx.x*256 + threadIdx.x;
  if (i < n) out[i] = f2b(in[i]);
}

// ---------- transpose im_emd (B,C,N) f32 -> At[(b*N+n)][c] bf16 ----------
__global__ __launch_bounds__(256) void transpose_kernel(const float* __restrict__ im, ushort* __restrict__ At){
  __shared__ ushort t[64][65];
  const int b = blockIdx.z;
  const int c0 = blockIdx.y*64, n0 = blockIdx.x*64;
  const int tx = threadIdx.x & 63, ty = threadIdx.x >> 6;
  #pragma unroll
  for (int i=0;i<16;++i){
    int c = ty + i*4;
    t[c][tx] = f2b(im[((size_t)(b*1024 + c0+c))*9216 + n0 + tx]);
  }
  __syncthreads();
  const int cx = threadIdx.x & 31, ny = threadIdx.x >> 5;
  #pragma unroll
  for (int j=0;j<8;++j){
    int n = ny + j*8;
    uint32_t u = (uint32_t)t[cx*2][n] | ((uint32_t)t[cx*2+1][n] << 16);
    *(uint32_t*)&At[((size_t)(b*9216 + n0+n))*1024 + c0 + cx*2] = u;
  }
}

// ---------- MFMA GEMM + fused column stats.  1D grid, XCD-swizzled, n-fast tiles ----------
// C[m][n] = sum_k A[m*K+k]*B[n*K+k];  sums[n]+=col sums, sqs[n]+=col sumsq (f32 atomics)
__global__ __launch_bounds__(256) void gemm_bt(
    const ushort* __restrict__ A, const ushort* __restrict__ Bm,
    ushort* __restrict__ Cm, float* __restrict__ sums, float* __restrict__ sqs,
    int NT, int N, int K)
{
  __shared__ __align__(16) ushort As[128*64];
  __shared__ __align__(16) ushort Bs[128*64];
  const int tid = threadIdx.x;
  const int l = tid & 63;
  const int w = tid >> 6;
  const int wm = w >> 1, wn = w & 1;
  // XCD-aware: give each XCD a contiguous chunk of logical tiles (grid % 8 == 0)
  const int chunk = gridDim.x >> 3;
  const int wg = (blockIdx.x & 7)*chunk + (blockIdx.x >> 3);
  const int tn = wg % NT, tm = wg / NT;
  const size_t n0 = (size_t)tn * 128;
  const size_t m0 = (size_t)tm * 128;
  const int lr = l & 15, lk = l >> 4;
  const int wbase = tid & ~63;   // wave-uniform

  f32x4 acc[4][4];
  #pragma unroll
  for (int i=0;i<4;++i)
    #pragma unroll
    for (int j=0;j<4;++j) acc[i][j] = (f32x4){0.f,0.f,0.f,0.f};

  for (int kt = 0; kt < K; kt += 64) {
    #pragma unroll
    for (int it=0; it<4; ++it) {
      int idx = it*256 + tid;
      int row = idx >> 3, c8 = idx & 7;
      int sc8 = c8 ^ (row & 7);   // pre-swizzled source column (permutes within the row's 128B segment)
      gll16(&A[(m0+row)*K + kt + sc8*8], &As[(it*256 + wbase)*8]);
      gll16(&Bm[(n0+row)*K + kt + sc8*8], &Bs[(it*256 + wbase)*8]);
    }
    __syncthreads();
    #pragma unroll
    for (int kk=0; kk<64; kk+=32) {
      bf16x8 af[4], bfr[4];
      #pragma unroll
      for (int i=0;i<4;++i){
        int row = wm*64 + i*16 + lr;
        af[i] = *(const bf16x8*)&As[row*64 + ((kk + lk*8) ^ ((row&7)<<3))];
      }
      #pragma unroll
      for (int j=0;j<4;++j){
        int row = wn*64 + j*16 + lr;
        bfr[j] = *(const bf16x8*)&Bs[row*64 + ((kk + lk*8) ^ ((row&7)<<3))];
      }
      #pragma unroll
      for (int i=0;i<4;++i)
        #pragma unroll
        for (int j=0;j<4;++j)
          acc[i][j] = __builtin_amdgcn_mfma_f32_16x16x32_bf16(af[i], bfr[j], acc[i][j], 0, 0, 0);
    }
    __syncthreads();
  }
  // C write
  #pragma unroll
  for (int i=0;i<4;++i)
    #pragma unroll
    for (int j=0;j<4;++j)
      #pragma unroll
      for (int r=0;r<4;++r) {
        size_t row = m0 + wm*64 + i*16 + lk*4 + r;
        size_t col = n0 + wn*64 + j*16 + lr;
        Cm[row*N + col] = f2b(acc[i][j][r]);
      }
  // fused column stats: per-thread partials -> wave reduce over lk -> atomics
  #pragma unroll
  for (int j=0;j<4;++j){
    float cs=0.f, cq=0.f;
    #pragma unroll
    for (int i=0;i<4;++i)
      #pragma unroll
      for (int r=0;r<4;++r){ float v=acc[i][j][r]; cs+=v; cq+=v*v; }
    cs += __shfl_xor(cs,16); cs += __shfl_xor(cs,32);
    cq += __shfl_xor(cq,16); cq += __shfl_xor(cq,32);
    if (lk==0){
      int col = (int)n0 + wn*64 + j*16 + lr;
      atomicAdd(&sums[col], cs);
      atomicAdd(&sqs [col], cq);
    }
  }
}

__global__ void bn_finalize(const float* __restrict__ sums, const float* __restrict__ sqs,
                            const float* __restrict__ g, const float* __restrict__ bb,
                            float* __restrict__ scale, float* __restrict__ shift, int C, float invn)
{
  int c = blockIdx.x*256 + threadIdx.x;
  if (c < C){
    float mu = sums[c]*invn;
    float var = sqs[c]*invn - mu*mu;
    float k = g[c] * rsqrtf(var + 1e-5f);
    scale[c] = k;
    shift[c] = bb[c] - mu*k;
  }
}

// ---------- BN + hardswish in place on y1 ----------
__global__ __launch_bounds__(256) void bn_hswish(ushort* __restrict__ y, const float* __restrict__ scale, const float* __restrict__ shift)
{
  __shared__ float sc[512], sh[512];
  for (int i=threadIdx.x;i<512;i+=256){ sc[i]=scale[i]; sh[i]=shift[i]; }
  __syncthreads();
  const size_t total = (size_t)73728*512/8;
  for (size_t idx = (size_t)blockIdx.x*256+threadIdx.x; idx < total; idx += (size_t)gridDim.x*256){
    uint4 u = *(uint4*)&y[idx*8];
    ushort* up = (ushort*)&u;
    int c0 = ((int)(idx & 63))*8;
    #pragma unroll
    for (int e=0;e<8;++e){
      float x = b2f(up[e])*sc[c0+e] + sh[c0+e];
      up[e] = f2b(hswish(x));
    }
    *(uint4*)&y[idx*8] = u;
  }
}

// ---------- q = text @ Wq^T (raw, f32) ----------
__global__ __launch_bounds__(256) void q_gemm(const float* __restrict__ text, const float* __restrict__ Wq, float* __restrict__ qraw)
{
  __shared__ __align__(16) float xr[512];
  const int t = blockIdx.x, tid = threadIdx.x;
  for (int i=tid;i<512;i+=256) xr[i] = text[t*512+i];
  __syncthreads();
  #pragma unroll
  for (int cj=0;cj<2;++cj){
    int c = cj*256+tid;
    const float4* wp = (const float4*)(Wq + (size_t)c*512);
    const float4* xp = (const float4*)xr;
    float a=0.f;
    for (int u=0;u<128;++u){
      float4 wv = wp[u], xv = xp[u];
      a += wv.x*xv.x + wv.y*xv.y + wv.z*xv.z + wv.w*xv.w;
    }
    qraw[t*512+c]=a;
  }
}

// ---------- q BN + fold K-BN scale into Qh (bf16), cQ[t,h] = 0.125*dot(q_bn, tk) ----------
__global__ __launch_bounds__(512) void q_bn_qh(const float* __restrict__ qraw, const float* __restrict__ g,
                                               const float* __restrict__ bb,
                                               const float* __restrict__ scale2, const float* __restrict__ shift2,
                                               ushort* __restrict__ Qh, float* __restrict__ cQ)
{
  const int c = threadIdx.x;
  const int h = c >> 6, d = c & 63;
  float s=0.f,q=0.f;
  for (int t=0;t<60;++t){ float v = qraw[t*512+c]; s+=v; q+=v*v; }
  float mu=s*(1.f/60.f), var=q*(1.f/60.f)-mu*mu;
  float k = g[c]*rsqrtf(var+1e-5f);
  float sh = bb[c]-mu*k;
  const float sk = scale2[h*192+d]*0.125f;
  const float tk = shift2[h*192+d]*0.125f;
  for (int t=0;t<60;++t){
    float qv = qraw[t*512+c]*k+sh;
    Qh[(h*64+t)*64+d] = f2b(qv*sk);
    float contrib = qv*tk;
    #pragma unroll
    for (int o=32;o>0;o>>=1) contrib += __shfl_xor(contrib,o);
    if (d==0) cQ[h*64+t] = contrib;
  }
  for (int t=60;t<64;++t) Qh[(h*64+t)*64+d] = 0;
}

// ---------- scores: S[bh][t][n] = Qh . Kraw + cQ + bias  (MFMA) ----------
__global__ __launch_bounds__(256) void scores_mfma(
    const ushort* __restrict__ Qh, const float* __restrict__ cQ,
    const ushort* __restrict__ kv, const float* __restrict__ biases,
    float* __restrict__ S)
{
  __shared__ __align__(16) ushort Qs[64*72];
  __shared__ float bias_l[10000];
  const int tid = threadIdx.x;
  const int l = tid & 63, w = tid >> 6;
  const int lr = l & 15, lk = l >> 4;
  const int h = blockIdx.y, b = blockIdx.z;
  const int n0 = blockIdx.x * 256;
  const int bh = b*8 + h;
  for (int cid = tid; cid < 512; cid += 256){
    int row = cid >> 3, c8 = cid & 7;
    *(uint4*)&Qs[row*72 + c8*8] = *(const uint4*)&Qh[(size_t)(h*64 + row)*64 + c8*8];
  }
  for (int i = tid; i < 10000; i += 256) bias_l[i] = biases[h*10000 + i];
  __syncthreads();
  f32x4 acc[4][4];
  #pragma unroll
  for (int i=0;i<4;++i)
    #pragma unroll
    for (int j=0;j<4;++j) acc[i][j]=(f32x4){0.f,0.f,0.f,0.f};
  const ushort* kbase = kv + ((size_t)(b*9216 + n0 + w*64))*1536 + h*192;
  #pragma unroll
  for (int kk=0; kk<64; kk+=32){
    bf16x8 af[4], bfr[4];
    #pragma unroll
    for (int i=0;i<4;++i) af[i] = *(const bf16x8*)&Qs[(i*16+lr)*72 + kk + lk*8];
    #pragma unroll
    for (int j=0;j<4;++j) bfr[j] = *(const bf16x8*)&kbase[(size_t)(j*16+lr)*1536 + kk + lk*8];
    #pragma unroll
    for (int i=0;i<4;++i)
      #pragma unroll
      for (int j=0;j<4;++j)
        acc[i][j] = __builtin_amdgcn_mfma_f32_16x16x32_bf16(af[i], bfr[j], acc[i][j], 0,0,0);
  }
  float* Sb = S + (size_t)bh*64*9216;
  #pragma unroll
  for (int j=0;j<4;++j){
    int n = n0 + w*64 + j*16 + lr;
    int py = n/96, px = n - py*96;
    const float* brow = &bias_l[100*py];
    #pragma unroll
    for (int i=0;i<4;++i){
      #pragma unroll
      for (int r=0;r<4;++r){
        int row = i*16 + lk*4 + r;
        if (row < 60){
          int dd = row - px; dd = dd<0?-dd:dd;
          Sb[(size_t)row*9216 + n] = acc[i][j][r] + cQ[h*64+row] + brow[dd];
        }
      }
    }
  }
}

// ---------- per-row softmax stats ----------
__global__ __launch_bounds__(256) void softmax_stats(const float* __restrict__ S, float* __restrict__ rmax_, float* __restrict__ rinv_)
{
  const int t = blockIdx.x, bh = blockIdx.y, tid = threadIdx.x;
  const float4* p = (const float4*)(S + ((size_t)bh*64 + t)*9216);
  float4 vals[9];
  float m = -1e30f;
  #pragma unroll
  for (int i=0;i<9;++i){ float4 v = p[i*256+tid]; vals[i]=v; m = fmaxf(m, fmaxf(fmaxf(v.x,v.y),fmaxf(v.z,v.w))); }
  #pragma unroll
  for (int o=32;o>0;o>>=1) m = fmaxf(m, __shfl_xor(m, o));
  __shared__ float wm[4], ws[4];
  if ((tid&63)==0) wm[tid>>6]=m;
  __syncthreads();
  m = fmaxf(fmaxf(wm[0],wm[1]),fmaxf(wm[2],wm[3]));
  float ssum=0.f;
  #pragma unroll
  for (int i=0;i<9;++i){ float4 v=vals[i]; ssum += __expf(v.x-m)+__expf(v.y-m)+__expf(v.z-m)+__expf(v.w-m); }
  #pragma unroll
  for (int o=32;o>0;o>>=1) ssum += __shfl_xor(ssum,o);
  if ((tid&63)==0) ws[tid>>6]=ssum;
  __syncthreads();
  if (tid==0){ rmax_[bh*64+t]=m; rinv_[bh*64+t]=1.f/(ws[0]+ws[1]+ws[2]+ws[3]); }
}

// ---------- PV: attn_o[b][t][h*128+dv] += P @ Vraw  (MFMA, V^T staged in LDS) ----------
__global__ __launch_bounds__(256) void pv_mfma(
    const float* __restrict__ S, const ushort* __restrict__ kv,
    const float* __restrict__ rmax_, const float* __restrict__ rinv_,
    float* __restrict__ attn_out)
{
  __shared__ ushort vt[128*68];
  const int tid = threadIdx.x;
  const int l = tid & 63, w = tid >> 6;
  const int lr = l & 15, lk = l >> 4;
  const int nc = blockIdx.x, h = blockIdx.y, b = blockIdx.z;
  const int bh = b*8+h;
  const size_t Sbase = (size_t)bh*64*9216;
  float rmv[4], riv[4];
  #pragma unroll
  for (int i=0;i<4;++i){ rmv[i]=rmax_[bh*64+i*16+lr]; riv[i]=rinv_[bh*64+i*16+lr]; }
  f32x4 acc[4][2];
  #pragma unroll
  for (int i=0;i<4;++i){ acc[i][0]=(f32x4){0.f,0.f,0.f,0.f}; acc[i][1]=(f32x4){0.f,0.f,0.f,0.f}; }
  for (int ks=0; ks<576; ks+=64){
    const int n0 = nc*576 + ks;
    if (ks) __syncthreads();
    #pragma unroll
    for (int c2=0;c2<4;++c2){
      int cid = c2*256 + tid;
      int row = cid >> 4, dv0 = (cid & 15)*8;
      uint4 vv = *(const uint4*)&kv[((size_t)(b*9216 + n0 + row))*1536 + h*192 + 64 + dv0];
      const ushort* vb8 = (const ushort*)&vv;
      #pragma unroll
      for (int e=0;e<8;++e) vt[(dv0+e)*68 + row] = vb8[e];
    }
    __syncthreads();
    #pragma unroll
    for (int kk=0; kk<64; kk+=32){
      bf16x8 pa[4], vb[2];
      #pragma unroll
      for (int i=0;i<4;++i){
        const float* sp = S + Sbase + (size_t)(i*16+lr)*9216 + n0 + kk + lk*8;
        float4 s0 = *(const float4*)sp, s1 = *(const float4*)(sp+4);
        float rm=rmv[i], ri=riv[i];
        bf16x8 t_;
        t_[0]=(short)f2b(__expf(s0.x-rm)*ri);
        t_[1]=(short)f2b(__expf(s0.y-rm)*ri);
        t_[2]=(short)f2b(__expf(s0.z-rm)*ri);
        t_[3]=(short)f2b(__expf(s0.w-rm)*ri);
        t_[4]=(short)f2b(__expf(s1.x-rm)*ri);
        t_[5]=(short)f2b(__expf(s1.y-rm)*ri);
        t_[6]=(short)f2b(__expf(s1.z-rm)*ri);
        t_[7]=(short)f2b(__expf(s1.w-rm)*ri);
        pa[i]=t_;
      }
      #pragma unroll
      for (int j=0;j<2;++j){
        const ushort* vp = &vt[(w*32 + j*16 + lr)*68 + kk + lk*8];
        uint2 a0 = *(const uint2*)vp, a1 = *(const uint2*)(vp+4);
        struct PP { uint2 a,b; } pp{a0,a1};
        vb[j] = __builtin_bit_cast(bf16x8, pp);
      }
      #pragma unroll
      for (int i=0;i<4;++i){
        acc[i][0] = __builtin_amdgcn_mfma_f32_16x16x32_bf16(pa[i], vb[0], acc[i][0],0,0,0);
        acc[i][1] = __builtin_amdgcn_mfma_f32_16x16x32_bf16(pa[i], vb[1], acc[i][1],0,0,0);
      }
    }
  }
  float* ob = attn_out + (size_t)(b*60)*1024 + h*128;
  #pragma unroll
  for (int j=0;j<2;++j){
    int dv = w*32 + j*16 + lr;
    #pragma unroll
    for (int i=0;i<4;++i)
      #pragma unroll
      for (int r=0;r<4;++r){
        int row = i*16 + lk*4 + r;
        if (row < 60) atomicAdd(&ob[(size_t)row*1024 + dv], acc[i][j][r]);
      }
  }
}

// ---------- row GEMM, 8 rows/block. MODE 0: id; 2: BN direct; 3: attn-BN map. hswish if MODE>=1 ----------
template<int CIN, int COUT, int MODE>
__global__ __launch_bounds__(256) void rowgemm8(
    const float* __restrict__ X, const float* __restrict__ Wt,
    const float* __restrict__ sc, const float* __restrict__ sh,
    float* __restrict__ out)
{
  __shared__ __align__(16) float xr[8][CIN];
  const int rb0 = blockIdx.x*8, tid = threadIdx.x;
  for (int i=tid; i<8*CIN; i+=256){
    int rr = i / CIN, cc = i % CIN;
    float v = X[(size_t)(rb0+rr)*CIN + cc];
    if constexpr (MODE==2) v = v*sc[cc]+sh[cc];
    if constexpr (MODE==3){ int idx = 64 + (cc&127) + (cc>>7)*192; v = v*sc[idx]+sh[idx]; }
    if constexpr (MODE>=1) v = hswish(v);
    xr[rr][cc]=v;
  }
  __syncthreads();
  #pragma unroll
  for (int cj=0; cj<COUT/256; ++cj){
    int c = cj*256 + tid;
    const float4* wp = (const float4*)(Wt + (size_t)c*CIN);
    float a[8] = {0.f,0.f,0.f,0.f,0.f,0.f,0.f,0.f};
    for (int u=0;u<CIN/4;++u){
      float4 wv = wp[u];
      #pragma unroll
      for (int rr=0;rr<8;++rr){
        float4 xv = *(const float4*)&xr[rr][u*4];
        a[rr] += wv.x*xv.x + wv.y*xv.y + wv.z*xv.z + wv.w*xv.w;
      }
    }
    #pragma unroll
    for (int rr=0;rr<8;++rr) out[(size_t)(rb0+rr)*COUT + c] = a[rr];
  }
}

template<int C>
__global__ void stats480(const float* __restrict__ X, const float* __restrict__ g,
                         const float* __restrict__ bb, float* __restrict__ sc, float* __restrict__ sh)
{
  int c = blockIdx.x*256 + threadIdx.x;
  float s=0.f, q=0.f;
  for (int r=0;r<480;++r){ float v = X[(size_t)r*C + c]; s+=v; q+=v*v; }
  float mu = s*(1.f/480.f), var = q*(1.f/480.f)-mu*mu;
  float k = g[c] * rsqrtf(var+1e-5f);
  sc[c]=k; sh[c]=bb[c] - mu*k;
}

__global__ void make_textd(const float* __restrict__ praw, const float* __restrict__ sp, const float* __restrict__ tp,
                           const float* __restrict__ text, float* __restrict__ textd)
{
  int i = blockIdx.x*256+threadIdx.x;
  if (i < 480*512){
    int c = i & 511, rb = i >> 9, t = rb % 60;
    textd[i] = text[t*512+c] + praw[i]*sp[c]+tp[c];
  }
}

__global__ void final_out(const float* __restrict__ f2raw, const float* __restrict__ sf, const float* __restrict__ tf,
                          const float* __restrict__ textd, float* __restrict__ outp)
{
  int i = blockIdx.x*256+threadIdx.x;
  if (i < 60*512){ int c = i & 511; outp[i] = f2raw[i]*sf[c]+tf[c] + textd[i]; }
}

extern "C" void kernel_launch(void* const* d_in, const int* in_sizes, int n_in,
                              void* d_out, int out_size, void* d_ws, size_t ws_size,
                              hipStream_t stream)
{
  (void)in_sizes; (void)n_in; (void)out_size; (void)ws_size;
  const float* im    = (const float*)d_in[0];
  const float* text  = (const float*)d_in[1];
  const float* W_dc  = (const float*)d_in[2];
  const float* g_dc  = (const float*)d_in[3];
  const float* b_dc  = (const float*)d_in[4];
  const float* W_kv  = (const float*)d_in[5];
  const float* g_kv  = (const float*)d_in[6];
  const float* b_kv  = (const float*)d_in[7];
  const float* W_q   = (const float*)d_in[8];
  const float* g_q   = (const float*)d_in[9];
  const float* b_q   = (const float*)d_in[10];
  const float* W_proj= (const float*)d_in[11];
  const float* g_proj= (const float*)d_in[12];
  const float* b_proj= (const float*)d_in[13];
  const float* biases= (const float*)d_in[14];
  const float* W_f1  = (const float*)d_in[15];
  const float* g_f1  = (const float*)d_in[16];
  const float* b_f1  = (const float*)d_in[17];
  const float* W_f2  = (const float*)d_in[18];
  const float* g_f2  = (const float*)d_in[19];
  const float* b_f2  = (const float*)d_in[20];
  float* outp = (float*)d_out;

  char* p = (char*)d_ws;
  auto alloc = [&](size_t bytes)->char*{ char* r = p; p += (bytes+255)&~(size_t)255; return r; };
  // zero zone (contiguous)
  float* s1_sum = (float*)alloc(512*4);
  float* s1_sq  = (float*)alloc(512*4);
  float* s2_sum = (float*)alloc(1536*4);
  float* s2_sq  = (float*)alloc(1536*4);
  float* attn_o = (float*)alloc((size_t)480*1024*4);
  float* zero_base = s1_sum; const int zero_n = 495616;
  // rest
  float* sc1 = (float*)alloc(512*4);
  float* sh1 = (float*)alloc(512*4);
  float* sc2 = (float*)alloc(1536*4);
  float* sh2 = (float*)alloc(1536*4);
  float* qraw = (float*)alloc(60*512*4);
  ushort* Qh = (ushort*)alloc((size_t)8*64*64*2);
  float* cQ = (float*)alloc(512*4);
  float* rmaxb = (float*)alloc(4096*4);
  float* rinvb = (float*)alloc(4096*4);
  float* proj_raw = (float*)alloc((size_t)480*512*4);
  float* sp=(float*)alloc(512*4); float* tp=(float*)alloc(512*4);
  float* textd=(float*)alloc((size_t)480*512*4);
  float* sf1=(float*)alloc(1024*4); float* tf1=(float*)alloc(1024*4);
  float* f1_raw=(float*)alloc((size_t)480*1024*4);
  float* sf2=(float*)alloc(512*4); float* tf2=(float*)alloc(512*4);
  float* f2_raw=(float*)alloc((size_t)480*512*4);
  ushort* Wdc_b = (ushort*)alloc((size_t)512*1024*2);
  ushort* Wkv_b = (ushort*)alloc((size_t)1536*512*2);
  ushort* y1 = (ushort*)alloc((size_t)73728*512*2);
  ushort* kv = (ushort*)alloc((size_t)73728*1536*2);
  ushort* At = (ushort*)alloc((size_t)73728*1024*2);
  float* S = (float*)At;  // alias: At dead after gemm1; S[64bh][64][9216] f32 == At bytes exactly

  zero_f32<<<1936,256,0,stream>>>(zero_base, zero_n);
  cvt_bf16<<<2048,256,0,stream>>>(W_dc, Wdc_b, 512*1024);
  cvt_bf16<<<3072,256,0,stream>>>(W_kv, Wkv_b, 1536*512);
  transpose_kernel<<<dim3(144,16,8),256,0,stream>>>(im, At);
  gemm_bt<<<2304,256,0,stream>>>(At, Wdc_b, y1, s1_sum, s1_sq, 4, 512, 1024);
  bn_finalize<<<2,256,0,stream>>>(s1_sum, s1_sq, g_dc, b_dc, sc1, sh1, 512, 1.f/73728.f);
  bn_hswish<<<2048,256,0,stream>>>(y1, sc1, sh1);
  gemm_bt<<<6912,256,0,stream>>>(y1, Wkv_b, kv, s2_sum, s2_sq, 12, 1536, 512);
  bn_finalize<<<6,256,0,stream>>>(s2_sum, s2_sq, g_kv, b_kv, sc2, sh2, 1536, 1.f/73728.f);
  q_gemm<<<60,256,0,stream>>>(text, W_q, qraw);
  q_bn_qh<<<1,512,0,stream>>>(qraw, g_q, b_q, sc2, sh2, Qh, cQ);
  scores_mfma<<<dim3(36,8,8),256,0,stream>>>(Qh, cQ, kv, biases, S);
  softmax_stats<<<dim3(60,64),256,0,stream>>>(S, rmaxb, rinvb);
  pv_mfma<<<dim3(16,8,8),256,0,stream>>>(S, kv, rmaxb, rinvb, attn_o);
  rowgemm8<1024,512,3><<<60,256,0,stream>>>(attn_o, W_proj, sc2, sh2, proj_raw);
  stats480<512><<<2,256,0,stream>>>(proj_raw, g_proj, b_proj, sp, tp);
  make_textd<<<960,256,0,stream>>>(proj_raw, sp, tp, text, textd);
  rowgemm8<512,1024,0><<<60,256,0,stream>>>(textd, W_f1, nullptr, nullptr, f1_raw);
  stats480<1024><<<4,256,0,stream>>>(f1_raw, g_f1, b_f1, sf1, tf1);
  rowgemm8<1024,512,2><<<60,256,0,stream>>>(f1_raw, W_f2, sf1, tf1, f2_raw);
  stats480<512><<<2,256,0,stream>>>(f2_raw, g_f2, b_f2, sf2, tf2);
  final_out<<<120,256,0,stream>>>(f2_raw, sf2, tf2, textd, outp);
}

// Round 6
// 763.455 us; speedup vs baseline: 2.5896x; 1.4577x over previous
//
#include <hip/hip_runtime.h>
#include <hip/hip_bf16.h>
#include <stdint.h>

typedef short bf16x8 __attribute__((ext_vector_type(8)));
typedef float f32x4 __attribute__((ext_vector_type(4)));

__device__ __forceinline__ float b2f(ushort u){ return __uint_as_float(((uint32_t)u)<<16); }
__device__ __forceinline__ ushort f2b(float f){
  uint32_t u = __float_as_uint(f);
  u += 0x7fffu + ((u>>16)&1u);
  return (ushort)(u>>16);
}
__device__ __forceinline__ float hswish(float x){ return x*fminf(fmaxf(x+3.f,0.f),6.f)*(1.f/6.f); }

// async global->LDS 16B (dest = wave-uniform base + lane*16)
__device__ __forceinline__ void gll16(const void* g, void* l){
  __builtin_amdgcn_global_load_lds((const __attribute__((address_space(1))) void*)g,
                                   (__attribute__((address_space(3))) void*)l, 16, 0, 0);
}

// ---------- zero scratch accumulators ----------
__global__ void zero_f32(float* __restrict__ p, int n){
  int i = blockIdx.x*256 + threadIdx.x;
  if (i < n) p[i] = 0.f;
}

// ---------- f32 -> bf16 ----------
__global__ void cvt_bf16(const float* __restrict__ in, ushort* __restrict__ out, int n){
  int i = blockIdx.x*256 + threadIdx.x;
  if (i < n) out[i] = f2b(in[i]);
}

// ---------- transpose im_emd (B,C,N) f32 -> At[(b*N+n)][c] bf16 (float4 loads, ushort4 stores) ----------
__global__ __launch_bounds__(256) void transpose_kernel(const float* __restrict__ im, ushort* __restrict__ At){
  __shared__ float tb[64][65];
  const int b = blockIdx.z, c0 = blockIdx.y*64, n0 = blockIdx.x*64;
  const int tid = threadIdx.x;
  const int cl = tid >> 2, q = tid & 3;
  #pragma unroll
  for (int it=0; it<4; ++it){
    int nn = q*4 + it*16;
    float4 v = *(const float4*)&im[((size_t)(b*1024 + c0 + cl))*9216 + n0 + nn];
    tb[cl][nn+0]=v.x; tb[cl][nn+1]=v.y; tb[cl][nn+2]=v.z; tb[cl][nn+3]=v.w;
  }
  __syncthreads();
  const int nr = tid >> 4, c4 = (tid & 15)*4;
  #pragma unroll
  for (int ps=0; ps<4; ++ps){
    int nn = nr + ps*16;
    ushort4 u;
    u.x = f2b(tb[c4+0][nn]); u.y = f2b(tb[c4+1][nn]);
    u.z = f2b(tb[c4+2][nn]); u.w = f2b(tb[c4+3][nn]);
    *(ushort4*)&At[((size_t)(b*9216 + n0 + nn))*1024 + c0 + c4] = u;
  }
}

// ---------- MFMA GEMM + fused column stats.  1D grid, XCD-swizzled, n-fast tiles ----------
__global__ __launch_bounds__(256) void gemm_bt(
    const ushort* __restrict__ A, const ushort* __restrict__ Bm,
    ushort* __restrict__ Cm, float* __restrict__ sums, float* __restrict__ sqs,
    int NT, int N, int K)
{
  __shared__ __align__(16) ushort As[128*64];
  __shared__ __align__(16) ushort Bs[128*64];
  const int tid = threadIdx.x;
  const int l = tid & 63;
  const int w = tid >> 6;
  const int wm = w >> 1, wn = w & 1;
  const int chunk = gridDim.x >> 3;
  const int wg = (blockIdx.x & 7)*chunk + (blockIdx.x >> 3);
  const int tn = wg % NT, tm = wg / NT;
  const size_t n0 = (size_t)tn * 128;
  const size_t m0 = (size_t)tm * 128;
  const int lr = l & 15, lk = l >> 4;
  const int wbase = tid & ~63;

  f32x4 acc[4][4];
  #pragma unroll
  for (int i=0;i<4;++i)
    #pragma unroll
    for (int j=0;j<4;++j) acc[i][j] = (f32x4){0.f,0.f,0.f,0.f};

  for (int kt = 0; kt < K; kt += 64) {
    #pragma unroll
    for (int it=0; it<4; ++it) {
      int idx = it*256 + tid;
      int row = idx >> 3, c8 = idx & 7;
      int sc8 = c8 ^ (row & 7);
      gll16(&A[(m0+row)*K + kt + sc8*8], &As[(it*256 + wbase)*8]);
      gll16(&Bm[(n0+row)*K + kt + sc8*8], &Bs[(it*256 + wbase)*8]);
    }
    __syncthreads();
    #pragma unroll
    for (int kk=0; kk<64; kk+=32) {
      bf16x8 af[4], bfr[4];
      #pragma unroll
      for (int i=0;i<4;++i){
        int row = wm*64 + i*16 + lr;
        af[i] = *(const bf16x8*)&As[row*64 + ((kk + lk*8) ^ ((row&7)<<3))];
      }
      #pragma unroll
      for (int j=0;j<4;++j){
        int row = wn*64 + j*16 + lr;
        bfr[j] = *(const bf16x8*)&Bs[row*64 + ((kk + lk*8) ^ ((row&7)<<3))];
      }
      #pragma unroll
      for (int i=0;i<4;++i)
        #pragma unroll
        for (int j=0;j<4;++j)
          acc[i][j] = __builtin_amdgcn_mfma_f32_16x16x32_bf16(af[i], bfr[j], acc[i][j], 0, 0, 0);
    }
    __syncthreads();
  }
  #pragma unroll
  for (int i=0;i<4;++i)
    #pragma unroll
    for (int j=0;j<4;++j)
      #pragma unroll
      for (int r=0;r<4;++r) {
        size_t row = m0 + wm*64 + i*16 + lk*4 + r;
        size_t col = n0 + wn*64 + j*16 + lr;
        Cm[row*N + col] = f2b(acc[i][j][r]);
      }
  #pragma unroll
  for (int j=0;j<4;++j){
    float cs=0.f, cq=0.f;
    #pragma unroll
    for (int i=0;i<4;++i)
      #pragma unroll
      for (int r=0;r<4;++r){ float v=acc[i][j][r]; cs+=v; cq+=v*v; }
    cs += __shfl_xor(cs,16); cs += __shfl_xor(cs,32);
    cq += __shfl_xor(cq,16); cq += __shfl_xor(cq,32);
    if (lk==0){
      int col = (int)n0 + wn*64 + j*16 + lr;
      atomicAdd(&sums[col], cs);
      atomicAdd(&sqs [col], cq);
    }
  }
}

__global__ void bn_finalize(const float* __restrict__ sums, const float* __restrict__ sqs,
                            const float* __restrict__ g, const float* __restrict__ bb,
                            float* __restrict__ scale, float* __restrict__ shift, int C, float invn)
{
  int c = blockIdx.x*256 + threadIdx.x;
  if (c < C){
    float mu = sums[c]*invn;
    float var = sqs[c]*invn - mu*mu;
    float k = g[c] * rsqrtf(var + 1e-5f);
    scale[c] = k;
    shift[c] = bb[c] - mu*k;
  }
}

// ---------- BN + hardswish in place on y1 ----------
__global__ __launch_bounds__(256) void bn_hswish(ushort* __restrict__ y, const float* __restrict__ scale, const float* __restrict__ shift)
{
  __shared__ float sc[512], sh[512];
  for (int i=threadIdx.x;i<512;i+=256){ sc[i]=scale[i]; sh[i]=shift[i]; }
  __syncthreads();
  const size_t total = (size_t)73728*512/8;
  for (size_t idx = (size_t)blockIdx.x*256+threadIdx.x; idx < total; idx += (size_t)gridDim.x*256){
    uint4 u = *(uint4*)&y[idx*8];
    ushort* up = (ushort*)&u;
    int c0 = ((int)(idx & 63))*8;
    #pragma unroll
    for (int e=0;e<8;++e){
      float x = b2f(up[e])*sc[c0+e] + sh[c0+e];
      up[e] = f2b(hswish(x));
    }
    *(uint4*)&y[idx*8] = u;
  }
}

// ---------- q = text @ Wq^T (raw, f32) ----------
__global__ __launch_bounds__(256) void q_gemm(const float* __restrict__ text, const float* __restrict__ Wq, float* __restrict__ qraw)
{
  __shared__ __align__(16) float xr[512];
  const int t = blockIdx.x, tid = threadIdx.x;
  for (int i=tid;i<512;i+=256) xr[i] = text[t*512+i];
  __syncthreads();
  #pragma unroll
  for (int cj=0;cj<2;++cj){
    int c = cj*256+tid;
    const float4* wp = (const float4*)(Wq + (size_t)c*512);
    const float4* xp = (const float4*)xr;
    float a=0.f;
    for (int u=0;u<128;++u){
      float4 wv = wp[u], xv = xp[u];
      a += wv.x*xv.x + wv.y*xv.y + wv.z*xv.z + wv.w*xv.w;
    }
    qraw[t*512+c]=a;
  }
}

// ---------- q BN + fold K-BN scale into Qh (bf16), cQ[t,h] = 0.125*dot(q_bn, tk) ----------
__global__ __launch_bounds__(512) void q_bn_qh(const float* __restrict__ qraw, const float* __restrict__ g,
                                               const float* __restrict__ bb,
                                               const float* __restrict__ scale2, const float* __restrict__ shift2,
                                               ushort* __restrict__ Qh, float* __restrict__ cQ)
{
  const int c = threadIdx.x;
  const int h = c >> 6, d = c & 63;
  float s=0.f,q=0.f;
  for (int t=0;t<60;++t){ float v = qraw[t*512+c]; s+=v; q+=v*v; }
  float mu=s*(1.f/60.f), var=q*(1.f/60.f)-mu*mu;
  float k = g[c]*rsqrtf(var+1e-5f);
  float sh = bb[c]-mu*k;
  const float sk = scale2[h*192+d]*0.125f;
  const float tk = shift2[h*192+d]*0.125f;
  for (int t=0;t<60;++t){
    float qv = qraw[t*512+c]*k+sh;
    Qh[(h*64+t)*64+d] = f2b(qv*sk);
    float contrib = qv*tk;
    #pragma unroll
    for (int o=32;o>0;o>>=1) contrib += __shfl_xor(contrib,o);
    if (d==0) cQ[h*64+t] = contrib;
  }
  for (int t=60;t<64;++t) Qh[(h*64+t)*64+d] = 0;
  if (d==0) for (int t=60;t<64;++t) cQ[h*64+t] = 0.f;
}

// ---------- flash attention: per (nc,h,b) block, online softmax over 1152-col chunk ----------
// outputs unnormalized O partials + (m,l) per row
__global__ __launch_bounds__(256) void attn_flash(
    const ushort* __restrict__ Qh, const float* __restrict__ cQ,
    const ushort* __restrict__ kv, const float* __restrict__ biases,
    float* __restrict__ Op, float* __restrict__ Mp, float* __restrict__ Lp)
{
  __shared__ __align__(16) ushort Qs[64*72];
  __shared__ __align__(16) ushort vt[128*68];
  __shared__ __align__(16) ushort Pw[4][16*72];
  __shared__ float bias_l[1200];
  __shared__ float cQs[64];
  const int tid = threadIdx.x;
  const int l = tid & 63, w = tid >> 6;
  const int lr = l & 15, lk = l >> 4;
  const int nc = blockIdx.x, h = blockIdx.y, b = blockIdx.z;
  const int bh = b*8+h;
  for (int cid = tid; cid < 512; cid += 256){
    int row = cid >> 3, c8 = cid & 7;
    *(uint4*)&Qs[row*72 + c8*8] = *(const uint4*)&Qh[(size_t)(h*64+row)*64 + c8*8];
  }
  for (int i = tid; i < 1200; i += 256) bias_l[i] = biases[h*10000 + nc*1200 + i];
  if (tid < 64) cQs[tid] = cQ[h*64 + tid];

  float m_run[4] = {-1e30f,-1e30f,-1e30f,-1e30f};
  float l_run[4] = {0.f,0.f,0.f,0.f};
  f32x4 acc_o[8];
  #pragma unroll
  for (int j=0;j<8;++j) acc_o[j] = (f32x4){0.f,0.f,0.f,0.f};
  __syncthreads();

  for (int tile=0; tile<18; ++tile){
    const int n0 = nc*1152 + tile*64;
    if (tile) __syncthreads();            // prev vt fully consumed
    #pragma unroll
    for (int c2=0;c2<4;++c2){
      int cid = c2*256 + tid;
      int row = cid >> 4, dv0 = (cid & 15)*8;
      uint4 vv = *(const uint4*)&kv[((size_t)(b*9216 + n0 + row))*1536 + h*192 + 64 + dv0];
      const ushort* vb8 = (const ushort*)&vv;
      #pragma unroll
      for (int e=0;e<8;++e) vt[(dv0+e)*68 + row] = vb8[e];
    }
    __syncthreads();
    // S-frags: rows w*16+lk*4+r, cols n0+j*16+lr
    f32x4 sa[4];
    #pragma unroll
    for (int j=0;j<4;++j) sa[j]=(f32x4){0.f,0.f,0.f,0.f};
    const ushort* kbase = kv + ((size_t)(b*9216 + n0))*1536 + h*192;
    #pragma unroll
    for (int kk=0; kk<64; kk+=32){
      bf16x8 af = *(const bf16x8*)&Qs[(w*16+lr)*72 + kk + lk*8];
      #pragma unroll
      for (int j=0;j<4;++j){
        bf16x8 bf_ = *(const bf16x8*)&kbase[(size_t)(j*16+lr)*1536 + kk + lk*8];
        sa[j] = __builtin_amdgcn_mfma_f32_16x16x32_bf16(af, bf_, sa[j], 0,0,0);
      }
    }
    // bias + cQ + tile max
    float mt[4] = {-1e30f,-1e30f,-1e30f,-1e30f};
    #pragma unroll
    for (int j=0;j<4;++j){
      int n = n0 + j*16 + lr;
      int py = n/96;
      int px = n - py*96;
      int pyl = py - nc*12;
      #pragma unroll
      for (int r=0;r<4;++r){
        int t = w*16 + lk*4 + r;
        int dd = t - px; dd = dd<0?-dd:dd;
        float s = sa[j][r] + cQs[t] + bias_l[pyl*100 + dd];
        sa[j][r] = s;
        mt[r] = fmaxf(mt[r], s);
      }
    }
    #pragma unroll
    for (int r=0;r<4;++r){
      #pragma unroll
      for (int o=1;o<16;o<<=1) mt[r] = fmaxf(mt[r], __shfl_xor(mt[r], o));
      float mnew = fmaxf(m_run[r], mt[r]);
      float ef = __expf(m_run[r] - mnew);
      m_run[r] = mnew;
      l_run[r] *= ef;
      #pragma unroll
      for (int j2=0;j2<8;++j2) acc_o[j2][r] *= ef;
    }
    // P tile -> LDS (per-wave), row sums
    float rs[4] = {0.f,0.f,0.f,0.f};
    #pragma unroll
    for (int j=0;j<4;++j)
      #pragma unroll
      for (int r=0;r<4;++r){
        float pe = __expf(sa[j][r] - m_run[r]);
        rs[r] += pe;
        Pw[w][(lk*4+r)*72 + j*16 + lr] = f2b(pe);
      }
    #pragma unroll
    for (int r=0;r<4;++r){
      #pragma unroll
      for (int o=1;o<16;o<<=1) rs[r] += __shfl_xor(rs[r], o);
      l_run[r] += rs[r];
    }
    // PV
    #pragma unroll
    for (int kk=0; kk<64; kk+=32){
      bf16x8 pa = *(const bf16x8*)&Pw[w][lr*72 + kk + lk*8];
      #pragma unroll
      for (int j2=0;j2<8;++j2){
        const ushort* vp = &vt[(j2*16+lr)*68 + kk + lk*8];
        uint2 a0 = *(const uint2*)vp, a1 = *(const uint2*)(vp+4);
        struct PP { uint2 a,b; } pp{a0,a1};
        bf16x8 vb = __builtin_bit_cast(bf16x8, pp);
        acc_o[j2] = __builtin_amdgcn_mfma_f32_16x16x32_bf16(pa, vb, acc_o[j2], 0,0,0);
      }
    }
  }
  // write partials
  float* ob = Op + (((size_t)nc*64 + bh)*64)*128;
  #pragma unroll
  for (int j2=0;j2<8;++j2)
    #pragma unroll
    for (int r=0;r<4;++r){
      int row = w*16 + lk*4 + r;
      ob[(size_t)row*128 + j2*16 + lr] = acc_o[j2][r];
    }
  if (lr == 0){
    #pragma unroll
    for (int r=0;r<4;++r){
      int row = w*16 + lk*4 + r;
      Mp[(nc*64+bh)*64 + row] = m_run[r];
      Lp[(nc*64+bh)*64 + row] = l_run[r];
    }
  }
}

// ---------- combine flash partials -> attn_o[b*60+t][h*128+dv] ----------
__global__ __launch_bounds__(128) void attn_combine(
    const float* __restrict__ Op, const float* __restrict__ Mp, const float* __restrict__ Lp,
    float* __restrict__ attn_o)
{
  const int t = blockIdx.x, bh = blockIdx.y;
  const int b = bh >> 3, h = bh & 7;
  const int dv = threadIdx.x;
  float mv[8];
  float m_g = -1e30f;
  #pragma unroll
  for (int i=0;i<8;++i){ mv[i] = Mp[(i*64+bh)*64 + t]; m_g = fmaxf(m_g, mv[i]); }
  float lsum = 0.f;
  #pragma unroll
  for (int i=0;i<8;++i) lsum += Lp[(i*64+bh)*64 + t] * __expf(mv[i]-m_g);
  float o = 0.f;
  #pragma unroll
  for (int i=0;i<8;++i)
    o += Op[(((size_t)i*64 + bh)*64 + t)*128 + dv] * __expf(mv[i]-m_g);
  attn_o[(size_t)(b*60+t)*1024 + h*128 + dv] = o / lsum;
}

// ---------- row GEMM, 8 rows/block, col-split grid.y. MODE 0: id; 2: BN; 3: attn-BN map ----------
template<int CIN, int COUT, int MODE>
__global__ __launch_bounds__(256) void rowgemm8(
    const float* __restrict__ X, const float* __restrict__ Wt,
    const float* __restrict__ sc, const float* __restrict__ sh,
    float* __restrict__ out)
{
  __shared__ __align__(16) float xr[8][CIN];
  const int rb0 = blockIdx.x*8, tid = threadIdx.x;
  for (int i=tid; i<8*CIN; i+=256){
    int rr = i / CIN, cc = i % CIN;
    float v = X[(size_t)(rb0+rr)*CIN + cc];
    if constexpr (MODE==2) v = v*sc[cc]+sh[cc];
    if constexpr (MODE==3){ int idx = 64 + (cc&127) + (cc>>7)*192; v = v*sc[idx]+sh[idx]; }
    if constexpr (MODE>=1) v = hswish(v);
    xr[rr][cc]=v;
  }
  __syncthreads();
  int c = blockIdx.y*256 + tid;
  const float4* wp = (const float4*)(Wt + (size_t)c*CIN);
  float a[8] = {0.f,0.f,0.f,0.f,0.f,0.f,0.f,0.f};
  for (int u=0;u<CIN/4;++u){
    float4 wv = wp[u];
    #pragma unroll
    for (int rr=0;rr<8;++rr){
      float4 xv = *(const float4*)&xr[rr][u*4];
      a[rr] += wv.x*xv.x + wv.y*xv.y + wv.z*xv.z + wv.w*xv.w;
    }
  }
  #pragma unroll
  for (int rr=0;rr<8;++rr) out[(size_t)(rb0+rr)*COUT + c] = a[rr];
}

template<int C>
__global__ void stats480(const float* __restrict__ X, const float* __restrict__ g,
                         const float* __restrict__ bb, float* __restrict__ sc, float* __restrict__ sh)
{
  int c = blockIdx.x*256 + threadIdx.x;
  float s=0.f, q=0.f;
  for (int r=0;r<480;++r){ float v = X[(size_t)r*C + c]; s+=v; q+=v*v; }
  float mu = s*(1.f/480.f), var = q*(1.f/480.f)-mu*mu;
  float k = g[c] * rsqrtf(var+1e-5f);
  sc[c]=k; sh[c]=bb[c] - mu*k;
}

__global__ void make_textd(const float* __restrict__ praw, const float* __restrict__ sp, const float* __restrict__ tp,
                           const float* __restrict__ text, float* __restrict__ textd)
{
  int i = blockIdx.x*256+threadIdx.x;
  if (i < 480*512){
    int c = i & 511, rb = i >> 9, t = rb % 60;
    textd[i] = text[t*512+c] + praw[i]*sp[c]+tp[c];
  }
}

__global__ void final_out(const float* __restrict__ f2raw, const float* __restrict__ sf, const float* __restrict__ tf,
                          const float* __restrict__ textd, float* __restrict__ outp)
{
  int i = blockIdx.x*256+threadIdx.x;
  if (i < 60*512){ int c = i & 511; outp[i] = f2raw[i]*sf[c]+tf[c] + textd[i]; }
}

extern "C" void kernel_launch(void* const* d_in, const int* in_sizes, int n_in,
                              void* d_out, int out_size, void* d_ws, size_t ws_size,
                              hipStream_t stream)
{
  (void)in_sizes; (void)n_in; (void)out_size; (void)ws_size;
  const float* im    = (const float*)d_in[0];
  const float* text  = (const float*)d_in[1];
  const float* W_dc  = (const float*)d_in[2];
  const float* g_dc  = (const float*)d_in[3];
  const float* b_dc  = (const float*)d_in[4];
  const float* W_kv  = (const float*)d_in[5];
  const float* g_kv  = (const float*)d_in[6];
  const float* b_kv  = (const float*)d_in[7];
  const float* W_q   = (const float*)d_in[8];
  const float* g_q   = (const float*)d_in[9];
  const float* b_q   = (const float*)d_in[10];
  const float* W_proj= (const float*)d_in[11];
  const float* g_proj= (const float*)d_in[12];
  const float* b_proj= (const float*)d_in[13];
  const float* biases= (const float*)d_in[14];
  const float* W_f1  = (const float*)d_in[15];
  const float* g_f1  = (const float*)d_in[16];
  const float* b_f1  = (const float*)d_in[17];
  const float* W_f2  = (const float*)d_in[18];
  const float* g_f2  = (const float*)d_in[19];
  const float* b_f2  = (const float*)d_in[20];
  float* outp = (float*)d_out;

  char* p = (char*)d_ws;
  auto alloc = [&](size_t bytes)->char*{ char* r = p; p += (bytes+255)&~(size_t)255; return r; };
  // zero zone (contiguous): the 4 stats accumulators
  float* s1_sum = (float*)alloc(512*4);
  float* s1_sq  = (float*)alloc(512*4);
  float* s2_sum = (float*)alloc(1536*4);
  float* s2_sq  = (float*)alloc(1536*4);
  float* zero_base = s1_sum; const int zero_n = 4096;
  // rest
  float* attn_o = (float*)alloc((size_t)480*1024*4);
  float* sc1 = (float*)alloc(512*4);
  float* sh1 = (float*)alloc(512*4);
  float* sc2 = (float*)alloc(1536*4);
  float* sh2 = (float*)alloc(1536*4);
  float* qraw = (float*)alloc(60*512*4);
  ushort* Qh = (ushort*)alloc((size_t)8*64*64*2);
  float* cQ = (float*)alloc(512*4);
  float* proj_raw = (float*)alloc((size_t)480*512*4);
  float* sp=(float*)alloc(512*4); float* tp=(float*)alloc(512*4);
  float* textd=(float*)alloc((size_t)480*512*4);
  float* sf1=(float*)alloc(1024*4); float* tf1=(float*)alloc(1024*4);
  float* f1_raw=(float*)alloc((size_t)480*1024*4);
  float* sf2=(float*)alloc(512*4); float* tf2=(float*)alloc(512*4);
  float* f2_raw=(float*)alloc((size_t)480*512*4);
  float* Op = (float*)alloc((size_t)8*64*64*128*4);
  float* Mp = (float*)alloc((size_t)8*64*64*4);
  float* Lp = (float*)alloc((size_t)8*64*64*4);
  ushort* Wdc_b = (ushort*)alloc((size_t)512*1024*2);
  ushort* Wkv_b = (ushort*)alloc((size_t)1536*512*2);
  ushort* y1 = (ushort*)alloc((size_t)73728*512*2);
  ushort* kv = (ushort*)alloc((size_t)73728*1536*2);
  ushort* At = (ushort*)alloc((size_t)73728*1024*2);

  zero_f32<<<16,256,0,stream>>>(zero_base, zero_n);
  cvt_bf16<<<2048,256,0,stream>>>(W_dc, Wdc_b, 512*1024);
  cvt_bf16<<<3072,256,0,stream>>>(W_kv, Wkv_b, 1536*512);
  transpose_kernel<<<dim3(144,16,8),256,0,stream>>>(im, At);
  gemm_bt<<<2304,256,0,stream>>>(At, Wdc_b, y1, s1_sum, s1_sq, 4, 512, 1024);
  bn_finalize<<<2,256,0,stream>>>(s1_sum, s1_sq, g_dc, b_dc, sc1, sh1, 512, 1.f/73728.f);
  bn_hswish<<<2048,256,0,stream>>>(y1, sc1, sh1);
  gemm_bt<<<6912,256,0,stream>>>(y1, Wkv_b, kv, s2_sum, s2_sq, 12, 1536, 512);
  bn_finalize<<<6,256,0,stream>>>(s2_sum, s2_sq, g_kv, b_kv, sc2, sh2, 1536, 1.f/73728.f);
  q_gemm<<<60,256,0,stream>>>(text, W_q, qraw);
  q_bn_qh<<<1,512,0,stream>>>(qraw, g_q, b_q, sc2, sh2, Qh, cQ);
  attn_flash<<<dim3(8,8,8),256,0,stream>>>(Qh, cQ, kv, biases, Op, Mp, Lp);
  attn_combine<<<dim3(60,64),128,0,stream>>>(Op, Mp, Lp, attn_o);
  rowgemm8<1024,512,3><<<dim3(60,2),256,0,stream>>>(attn_o, W_proj, sc2, sh2, proj_raw);
  stats480<512><<<2,256,0,stream>>>(proj_raw, g_proj, b_proj, sp, tp);
  make_textd<<<960,256,0,stream>>>(proj_raw, sp, tp, text, textd);
  rowgemm8<512,1024,0><<<dim3(60,4),256,0,stream>>>(textd, W_f1, nullptr, nullptr, f1_raw);
  stats480<1024><<<4,256,0,stream>>>(f1_raw, g_f1, b_f1, sf1, tf1);
  rowgemm8<1024,512,2><<<dim3(60,2),256,0,stream>>>(f1_raw, W_f2, sf1, tf1, f2_raw);
  stats480<512><<<2,256,0,stream>>>(f2_raw, g_f2, b_f2, sf2, tf2);
  final_out<<<120,256,0,stream>>>(f2_raw, sf2, tf2, textd, outp);
}

// Round 7
// 747.229 us; speedup vs baseline: 2.6458x; 1.0217x over previous
//
#include <hip/hip_runtime.h>
#include <hip/hip_bf16.h>
#include <stdint.h>

typedef short bf16x8 __attribute__((ext_vector_type(8)));
typedef float f32x4 __attribute__((ext_vector_type(4)));

__device__ __forceinline__ float b2f(ushort u){ return __uint_as_float(((uint32_t)u)<<16); }
__device__ __forceinline__ ushort f2b(float f){
  uint32_t u = __float_as_uint(f);
  u += 0x7fffu + ((u>>16)&1u);
  return (ushort)(u>>16);
}
__device__ __forceinline__ float hswish(float x){ return x*fminf(fmaxf(x+3.f,0.f),6.f)*(1.f/6.f); }

// async global->LDS 16B (dest = wave-uniform base + lane*16)
__device__ __forceinline__ void gll16(const void* g, void* l){
  __builtin_amdgcn_global_load_lds((const __attribute__((address_space(1))) void*)g,
                                   (__attribute__((address_space(3))) void*)l, 16, 0, 0);
}

// ---------- init: zero stats accumulators + convert weights to bf16 ----------
__global__ void init_kernel(const float* __restrict__ Wdc, const float* __restrict__ Wkv,
                            ushort* __restrict__ Wdc_b, ushort* __restrict__ Wkv_b,
                            float* __restrict__ zbase){
  int i = blockIdx.x*256 + threadIdx.x;
  if (i < 8192) zbase[i] = 0.f;
  for (int j=i; j<512*1024; j+=262144) Wdc_b[j] = f2b(Wdc[j]);
  for (int j=i; j<1536*512; j+=262144) Wkv_b[j] = f2b(Wkv[j]);
}

// ---------- transpose im_emd (B,C,N) f32 -> At[(b*N+n)][c] bf16 ----------
__global__ __launch_bounds__(256) void transpose_kernel(const float* __restrict__ im, ushort* __restrict__ At){
  __shared__ float tb[64][65];
  const int b = blockIdx.z, c0 = blockIdx.y*64, n0 = blockIdx.x*64;
  const int tid = threadIdx.x;
  const int cl = tid >> 2, q = tid & 3;
  #pragma unroll
  for (int it=0; it<4; ++it){
    int nn = q*4 + it*16;
    float4 v = *(const float4*)&im[((size_t)(b*1024 + c0 + cl))*9216 + n0 + nn];
    tb[cl][nn+0]=v.x; tb[cl][nn+1]=v.y; tb[cl][nn+2]=v.z; tb[cl][nn+3]=v.w;
  }
  __syncthreads();
  const int nr = tid >> 4, c4 = (tid & 15)*4;
  #pragma unroll
  for (int ps=0; ps<4; ++ps){
    int nn = nr + ps*16;
    ushort4 u;
    u.x = f2b(tb[c4+0][nn]); u.y = f2b(tb[c4+1][nn]);
    u.z = f2b(tb[c4+2][nn]); u.w = f2b(tb[c4+3][nn]);
    *(ushort4*)&At[((size_t)(b*9216 + n0 + nn))*1024 + c0 + c4] = u;
  }
}

// ---------- MFMA GEMM + fused column stats. 1D grid, XCD-swizzled, n-fast ----------
// SPLIT=0: C -> Cm[m][N].  SPLIT=1 (kv): K cols -> Kbuf[b][n][h][64], V cols -> Vt[b][h][dv][9216]
template<int SPLIT>
__global__ __launch_bounds__(256) void gemm_bt(
    const ushort* __restrict__ A, const ushort* __restrict__ Bm,
    ushort* __restrict__ Cm, ushort* __restrict__ Vt,
    float* __restrict__ sums, float* __restrict__ sqs,
    int NT, int N, int K)
{
  __shared__ __align__(16) ushort As[128*64];
  __shared__ __align__(16) ushort Bs[128*64];
  const int tid = threadIdx.x;
  const int l = tid & 63;
  const int w = tid >> 6;
  const int wm = w >> 1, wn = w & 1;
  const int chunk = gridDim.x >> 3;
  const int wg = (blockIdx.x & 7)*chunk + (blockIdx.x >> 3);
  const int tn = wg % NT, tm = wg / NT;
  const size_t n0 = (size_t)tn * 128;
  const size_t m0 = (size_t)tm * 128;
  const int lr = l & 15, lk = l >> 4;
  const int wbase = tid & ~63;

  f32x4 acc[4][4];
  #pragma unroll
  for (int i=0;i<4;++i)
    #pragma unroll
    for (int j=0;j<4;++j) acc[i][j] = (f32x4){0.f,0.f,0.f,0.f};

  for (int kt = 0; kt < K; kt += 64) {
    #pragma unroll
    for (int it=0; it<4; ++it) {
      int idx = it*256 + tid;
      int row = idx >> 3, c8 = idx & 7;
      int sc8 = c8 ^ (row & 7);
      gll16(&A[(m0+row)*K + kt + sc8*8], &As[(it*256 + wbase)*8]);
      gll16(&Bm[(n0+row)*K + kt + sc8*8], &Bs[(it*256 + wbase)*8]);
    }
    __syncthreads();
    #pragma unroll
    for (int kk=0; kk<64; kk+=32) {
      bf16x8 af[4], bfr[4];
      #pragma unroll
      for (int i=0;i<4;++i){
        int row = wm*64 + i*16 + lr;
        af[i] = *(const bf16x8*)&As[row*64 + ((kk + lk*8) ^ ((row&7)<<3))];
      }
      #pragma unroll
      for (int j=0;j<4;++j){
        int row = wn*64 + j*16 + lr;
        bfr[j] = *(const bf16x8*)&Bs[row*64 + ((kk + lk*8) ^ ((row&7)<<3))];
      }
      #pragma unroll
      for (int i=0;i<4;++i)
        #pragma unroll
        for (int j=0;j<4;++j)
          acc[i][j] = __builtin_amdgcn_mfma_f32_16x16x32_bf16(af[i], bfr[j], acc[i][j], 0, 0, 0);
    }
    __syncthreads();
  }
  if constexpr (SPLIT==0){
    #pragma unroll
    for (int i=0;i<4;++i)
      #pragma unroll
      for (int j=0;j<4;++j)
        #pragma unroll
        for (int r=0;r<4;++r) {
          size_t row = m0 + wm*64 + i*16 + lk*4 + r;
          size_t col = n0 + wn*64 + j*16 + lr;
          Cm[row*N + col] = f2b(acc[i][j][r]);
        }
  } else {
    const int bq = (int)(m0/9216);
    const int nbase = (int)(m0 - (size_t)bq*9216);
    #pragma unroll
    for (int j=0;j<4;++j){
      int c = (int)n0 + wn*64 + j*16 + lr;
      int h = c/192, rcol = c - h*192;
      #pragma unroll
      for (int i=0;i<4;++i){
        int nrow = nbase + wm*64 + i*16 + lk*4;
        if (rcol < 64){
          ushort* kb = Cm + ((size_t)(bq*9216 + nrow))*512 + h*64 + rcol;
          #pragma unroll
          for (int r=0;r<4;++r) kb[(size_t)r*512] = f2b(acc[i][j][r]);
        } else {
          int dv = rcol - 64;
          ushort4 u;
          u.x=f2b(acc[i][j][0]); u.y=f2b(acc[i][j][1]);
          u.z=f2b(acc[i][j][2]); u.w=f2b(acc[i][j][3]);
          *(ushort4*)&Vt[((size_t)((bq*8+h)*128 + dv))*9216 + nrow] = u;
        }
      }
    }
  }
  #pragma unroll
  for (int j=0;j<4;++j){
    float cs=0.f, cq=0.f;
    #pragma unroll
    for (int i=0;i<4;++i)
      #pragma unroll
      for (int r=0;r<4;++r){ float v=acc[i][j][r]; cs+=v; cq+=v*v; }
    cs += __shfl_xor(cs,16); cs += __shfl_xor(cs,32);
    cq += __shfl_xor(cq,16); cq += __shfl_xor(cq,32);
    if (lk==0){
      int col = (int)n0 + wn*64 + j*16 + lr;
      atomicAdd(&sums[col], cs);
      atomicAdd(&sqs [col], cq);
    }
  }
}

__global__ void bn_finalize(const float* __restrict__ sums, const float* __restrict__ sqs,
                            const float* __restrict__ g, const float* __restrict__ bb,
                            float* __restrict__ scale, float* __restrict__ shift, int C, float invn)
{
  int c = blockIdx.x*256 + threadIdx.x;
  if (c < C){
    float mu = sums[c]*invn;
    float var = sqs[c]*invn - mu*mu;
    float k = g[c] * rsqrtf(var + 1e-5f);
    scale[c] = k;
    shift[c] = bb[c] - mu*k;
  }
}

// ---------- BN + hardswish in place on y1 ----------
__global__ __launch_bounds__(256) void bn_hswish(ushort* __restrict__ y, const float* __restrict__ scale, const float* __restrict__ shift)
{
  __shared__ float sc[512], sh[512];
  for (int i=threadIdx.x;i<512;i+=256){ sc[i]=scale[i]; sh[i]=shift[i]; }
  __syncthreads();
  const size_t total = (size_t)73728*512/8;
  for (size_t idx = (size_t)blockIdx.x*256+threadIdx.x; idx < total; idx += (size_t)gridDim.x*256){
    uint4 u = *(uint4*)&y[idx*8];
    ushort* up = (ushort*)&u;
    int c0 = ((int)(idx & 63))*8;
    #pragma unroll
    for (int e=0;e<8;++e){
      float x = b2f(up[e])*sc[c0+e] + sh[c0+e];
      up[e] = f2b(hswish(x));
    }
    *(uint4*)&y[idx*8] = u;
  }
}

// ---------- q = text @ Wq^T (raw, f32) ----------
__global__ __launch_bounds__(256) void q_gemm(const float* __restrict__ text, const float* __restrict__ Wq, float* __restrict__ qraw)
{
  __shared__ __align__(16) float xr[512];
  const int t = blockIdx.x, tid = threadIdx.x;
  for (int i=tid;i<512;i+=256) xr[i] = text[t*512+i];
  __syncthreads();
  #pragma unroll
  for (int cj=0;cj<2;++cj){
    int c = cj*256+tid;
    const float4* wp = (const float4*)(Wq + (size_t)c*512);
    const float4* xp = (const float4*)xr;
    float a=0.f;
    for (int u=0;u<128;++u){
      float4 wv = wp[u], xv = xp[u];
      a += wv.x*xv.x + wv.y*xv.y + wv.z*xv.z + wv.w*xv.w;
    }
    qraw[t*512+c]=a;
  }
}

// ---------- q BN + fold K-BN scale into Qh (bf16), cQ[t,h] = 0.125*dot(q_bn, tk) ----------
__global__ __launch_bounds__(512) void q_bn_qh(const float* __restrict__ qraw, const float* __restrict__ g,
                                               const float* __restrict__ bb,
                                               const float* __restrict__ scale2, const float* __restrict__ shift2,
                                               ushort* __restrict__ Qh, float* __restrict__ cQ)
{
  const int c = threadIdx.x;
  const int h = c >> 6, d = c & 63;
  float s=0.f,q=0.f;
  for (int t=0;t<60;++t){ float v = qraw[t*512+c]; s+=v; q+=v*v; }
  float mu=s*(1.f/60.f), var=q*(1.f/60.f)-mu*mu;
  float k = g[c]*rsqrtf(var+1e-5f);
  float sh = bb[c]-mu*k;
  const float sk = scale2[h*192+d]*0.125f;
  const float tk = shift2[h*192+d]*0.125f;
  for (int t=0;t<60;++t){
    float qv = qraw[t*512+c]*k+sh;
    Qh[(h*64+t)*64+d] = f2b(qv*sk);
    float contrib = qv*tk;
    #pragma unroll
    for (int o=32;o>0;o>>=1) contrib += __shfl_xor(contrib,o);
    if (d==0) cQ[h*64+t] = contrib;
  }
  for (int t=60;t<64;++t) Qh[(h*64+t)*64+d] = 0;
  if (d==0) for (int t=60;t<64;++t) cQ[h*64+t] = 0.f;
}

// ---------- flash attention over 1152-col chunk; V staged async from pre-transposed Vt ----------
__global__ __launch_bounds__(256) void attn_flash(
    const ushort* __restrict__ Qh, const float* __restrict__ cQ,
    const ushort* __restrict__ Kbuf, const ushort* __restrict__ Vt,
    const float* __restrict__ biases,
    float* __restrict__ Op, float* __restrict__ Mp, float* __restrict__ Lp)
{
  __shared__ __align__(16) ushort Qs[64*72];
  __shared__ __align__(16) ushort vt[128*64];
  __shared__ __align__(16) ushort Pw[4][16*72];
  __shared__ float bias_l[1200];
  __shared__ float cQs[64];
  const int tid = threadIdx.x;
  const int l = tid & 63, w = tid >> 6;
  const int lr = l & 15, lk = l >> 4;
  const int nc = blockIdx.x, h = blockIdx.y, b = blockIdx.z;
  const int bh = b*8+h;
  const int wbase = tid & ~63;
  for (int cid = tid; cid < 512; cid += 256){
    int row = cid >> 3, c8 = cid & 7;
    *(uint4*)&Qs[row*72 + c8*8] = *(const uint4*)&Qh[(size_t)(h*64+row)*64 + c8*8];
  }
  for (int i = tid; i < 1200; i += 256) bias_l[i] = biases[h*10000 + nc*1200 + i];
  if (tid < 64) cQs[tid] = cQ[h*64 + tid];

  const ushort* vsrc = Vt + (size_t)bh*128*9216;
  const ushort* kchunk = Kbuf + (size_t)b*9216*512 + h*64;

  float m_run[4] = {-1e30f,-1e30f,-1e30f,-1e30f};
  float l_run[4] = {0.f,0.f,0.f,0.f};
  f32x4 acc_o[8];
  #pragma unroll
  for (int j=0;j<8;++j) acc_o[j] = (f32x4){0.f,0.f,0.f,0.f};
  __syncthreads();

  for (int tile=0; tile<18; ++tile){
    const int n0 = nc*1152 + tile*64;
    if (tile) __syncthreads();            // prev vt fully consumed
    // stage V^T tile: rows dv=0..127, cols n0..n0+63, source pre-swizzled
    #pragma unroll
    for (int it=0; it<4; ++it){
      int idx = it*256 + tid;
      int row = idx >> 3, c8 = idx & 7;
      int sc8 = c8 ^ (row & 7);
      gll16(&vsrc[(size_t)row*9216 + n0 + sc8*8], &vt[(it*256 + wbase)*8]);
    }
    __syncthreads();
    // S-frags: rows t=w*16+lk*4+r, cols n0+j*16+lr (K direct from Kbuf, L2)
    f32x4 sa[4];
    #pragma unroll
    for (int j=0;j<4;++j) sa[j]=(f32x4){0.f,0.f,0.f,0.f};
    const ushort* kbase = kchunk + (size_t)n0*512;
    __builtin_amdgcn_s_setprio(1);
    #pragma unroll
    for (int kk=0; kk<64; kk+=32){
      bf16x8 af = *(const bf16x8*)&Qs[(w*16+lr)*72 + kk + lk*8];
      #pragma unroll
      for (int j=0;j<4;++j){
        bf16x8 bf_ = *(const bf16x8*)&kbase[(size_t)(j*16+lr)*512 + kk + lk*8];
        sa[j] = __builtin_amdgcn_mfma_f32_16x16x32_bf16(af, bf_, sa[j], 0,0,0);
      }
    }
    __builtin_amdgcn_s_setprio(0);
    // bias + cQ + tile max
    float mt[4] = {-1e30f,-1e30f,-1e30f,-1e30f};
    #pragma unroll
    for (int j=0;j<4;++j){
      int n = n0 + j*16 + lr;
      int py = n/96;
      int px = n - py*96;
      int pyl = py - nc*12;
      #pragma unroll
      for (int r=0;r<4;++r){
        int t = w*16 + lk*4 + r;
        int dd = t - px; dd = dd<0?-dd:dd;
        float s = sa[j][r] + cQs[t] + bias_l[pyl*100 + dd];
        sa[j][r] = s;
        mt[r] = fmaxf(mt[r], s);
      }
    }
    #pragma unroll
    for (int r=0;r<4;++r){
      #pragma unroll
      for (int o=1;o<16;o<<=1) mt[r] = fmaxf(mt[r], __shfl_xor(mt[r], o));
      float mnew = fmaxf(m_run[r], mt[r]);
      float ef = __expf(m_run[r] - mnew);
      m_run[r] = mnew;
      l_run[r] *= ef;
      #pragma unroll
      for (int j2=0;j2<8;++j2) acc_o[j2][r] *= ef;
    }
    // P tile -> per-wave LDS, row sums
    float rs[4] = {0.f,0.f,0.f,0.f};
    #pragma unroll
    for (int j=0;j<4;++j)
      #pragma unroll
      for (int r=0;r<4;++r){
        float pe = __expf(sa[j][r] - m_run[r]);
        rs[r] += pe;
        Pw[w][(lk*4+r)*72 + j*16 + lr] = f2b(pe);
      }
    #pragma unroll
    for (int r=0;r<4;++r){
      #pragma unroll
      for (int o=1;o<16;o<<=1) rs[r] += __shfl_xor(rs[r], o);
      l_run[r] += rs[r];
    }
    // PV: B-frags from swizzled vt
    __builtin_amdgcn_s_setprio(1);
    #pragma unroll
    for (int kk=0; kk<64; kk+=32){
      bf16x8 pa = *(const bf16x8*)&Pw[w][lr*72 + kk + lk*8];
      #pragma unroll
      for (int j2=0;j2<8;++j2){
        int dv = j2*16 + lr;
        bf16x8 vb = *(const bf16x8*)&vt[dv*64 + ((kk + lk*8) ^ ((dv&7)<<3))];
        acc_o[j2] = __builtin_amdgcn_mfma_f32_16x16x32_bf16(pa, vb, acc_o[j2], 0,0,0);
      }
    }
    __builtin_amdgcn_s_setprio(0);
  }
  // write partials
  float* ob = Op + (((size_t)nc*64 + bh)*64)*128;
  #pragma unroll
  for (int j2=0;j2<8;++j2)
    #pragma unroll
    for (int r=0;r<4;++r){
      int row = w*16 + lk*4 + r;
      ob[(size_t)row*128 + j2*16 + lr] = acc_o[j2][r];
    }
  if (lr == 0){
    #pragma unroll
    for (int r=0;r<4;++r){
      int row = w*16 + lk*4 + r;
      Mp[(nc*64+bh)*64 + row] = m_run[r];
      Lp[(nc*64+bh)*64 + row] = l_run[r];
    }
  }
}

// ---------- combine flash partials -> attn_o[b*60+t][h*128+dv] ----------
__global__ __launch_bounds__(128) void attn_combine(
    const float* __restrict__ Op, const float* __restrict__ Mp, const float* __restrict__ Lp,
    float* __restrict__ attn_o)
{
  const int t = blockIdx.x, bh = blockIdx.y;
  const int b = bh >> 3, h = bh & 7;
  const int dv = threadIdx.x;
  float mv[8];
  float m_g = -1e30f;
  #pragma unroll
  for (int i=0;i<8;++i){ mv[i] = Mp[(i*64+bh)*64 + t]; m_g = fmaxf(m_g, mv[i]); }
  float lsum = 0.f;
  #pragma unroll
  for (int i=0;i<8;++i) lsum += Lp[(i*64+bh)*64 + t] * __expf(mv[i]-m_g);
  float o = 0.f;
  #pragma unroll
  for (int i=0;i<8;++i)
    o += Op[(((size_t)i*64 + bh)*64 + t)*128 + dv] * __expf(mv[i]-m_g);
  attn_o[(size_t)(b*60+t)*1024 + h*128 + dv] = o / lsum;
}

// ---------- row GEMM, 8 rows/block, col-split grid.y, fused output stats (atomics) ----------
// MODE 0: id; 2: BN(sc,sh)+hswish; 3: attn-BN map+hswish; 4: textd = text + X*sc+sh (id, store textd)
template<int CIN, int COUT, int MODE>
__global__ __launch_bounds__(256) void rowgemm8(
    const float* __restrict__ X, const float* __restrict__ Wt,
    const float* __restrict__ sc, const float* __restrict__ sh,
    const float* __restrict__ text, float* __restrict__ textd,
    float* __restrict__ out, float* __restrict__ osum, float* __restrict__ osq)
{
  __shared__ __align__(16) float xr[8][CIN];
  const int rb0 = blockIdx.x*8, tid = threadIdx.x;
  for (int i=tid; i<8*CIN; i+=256){
    int rr = i / CIN, cc = i % CIN;
    float v = X[(size_t)(rb0+rr)*CIN + cc];
    if constexpr (MODE==2){ v = v*sc[cc]+sh[cc]; v = hswish(v); }
    if constexpr (MODE==3){ int idx = 64 + (cc&127) + (cc>>7)*192; v = v*sc[idx]+sh[idx]; v = hswish(v); }
    if constexpr (MODE==4){
      int t = (rb0+rr) % 60;
      v = text[t*CIN+cc] + v*sc[cc]+sh[cc];
      if (blockIdx.y == 0) textd[(size_t)(rb0+rr)*CIN + cc] = v;
    }
    xr[rr][cc]=v;
  }
  __syncthreads();
  int c = blockIdx.y*256 + tid;
  const float4* wp = (const float4*)(Wt + (size_t)c*CIN);
  float a[8] = {0.f,0.f,0.f,0.f,0.f,0.f,0.f,0.f};
  for (int u=0;u<CIN/4;++u){
    float4 wv = wp[u];
    #pragma unroll
    for (int rr=0;rr<8;++rr){
      float4 xv = *(const float4*)&xr[rr][u*4];
      a[rr] += wv.x*xv.x + wv.y*xv.y + wv.z*xv.z + wv.w*xv.w;
    }
  }
  float ps=0.f, pq=0.f;
  #pragma unroll
  for (int rr=0;rr<8;++rr){
    out[(size_t)(rb0+rr)*COUT + c] = a[rr];
    ps += a[rr]; pq += a[rr]*a[rr];
  }
  atomicAdd(&osum[c], ps);
  atomicAdd(&osq [c], pq);
}

__global__ void final_out(const float* __restrict__ f2raw, const float* __restrict__ sf, const float* __restrict__ tf,
                          const float* __restrict__ textd, float* __restrict__ outp)
{
  int i = blockIdx.x*256+threadIdx.x;
  if (i < 60*512){ int c = i & 511; outp[i] = f2raw[i]*sf[c]+tf[c] + textd[i]; }
}

extern "C" void kernel_launch(void* const* d_in, const int* in_sizes, int n_in,
                              void* d_out, int out_size, void* d_ws, size_t ws_size,
                              hipStream_t stream)
{
  (void)in_sizes; (void)n_in; (void)out_size; (void)ws_size;
  const float* im    = (const float*)d_in[0];
  const float* text  = (const float*)d_in[1];
  const float* W_dc  = (const float*)d_in[2];
  const float* g_dc  = (const float*)d_in[3];
  const float* b_dc  = (const float*)d_in[4];
  const float* W_kv  = (const float*)d_in[5];
  const float* g_kv  = (const float*)d_in[6];
  const float* b_kv  = (const float*)d_in[7];
  const float* W_q   = (const float*)d_in[8];
  const float* g_q   = (const float*)d_in[9];
  const float* b_q   = (const float*)d_in[10];
  const float* W_proj= (const float*)d_in[11];
  const float* g_proj= (const float*)d_in[12];
  const float* b_proj= (const float*)d_in[13];
  const float* biases= (const float*)d_in[14];
  const float* W_f1  = (const float*)d_in[15];
  const float* g_f1  = (const float*)d_in[16];
  const float* b_f1  = (const float*)d_in[17];
  const float* W_f2  = (const float*)d_in[18];
  const float* g_f2  = (const float*)d_in[19];
  const float* b_f2  = (const float*)d_in[20];
  float* outp = (float*)d_out;

  char* p = (char*)d_ws;
  auto alloc = [&](size_t bytes)->char*{ char* r = p; p += (bytes+255)&~(size_t)255; return r; };
  // zero zone (contiguous, 8192 floats): gemm stats + rowgemm stats
  float* s1_sum = (float*)alloc(512*4);
  float* s1_sq  = (float*)alloc(512*4);
  float* s2_sum = (float*)alloc(1536*4);
  float* s2_sq  = (float*)alloc(1536*4);
  float* s3_sum = (float*)alloc(512*4);   // proj
  float* s3_sq  = (float*)alloc(512*4);
  float* s4_sum = (float*)alloc(1024*4);  // f1
  float* s4_sq  = (float*)alloc(1024*4);
  float* s5_sum = (float*)alloc(512*4);   // f2
  float* s5_sq  = (float*)alloc(512*4);
  float* zero_base = s1_sum;
  // rest
  float* attn_o = (float*)alloc((size_t)480*1024*4);
  float* sc1 = (float*)alloc(512*4);
  float* sh1 = (float*)alloc(512*4);
  float* sc2 = (float*)alloc(1536*4);
  float* sh2 = (float*)alloc(1536*4);
  float* qraw = (float*)alloc(60*512*4);
  ushort* Qh = (ushort*)alloc((size_t)8*64*64*2);
  float* cQ = (float*)alloc(512*4);
  float* proj_raw = (float*)alloc((size_t)480*512*4);
  float* sp=(float*)alloc(512*4); float* tp=(float*)alloc(512*4);
  float* textd=(float*)alloc((size_t)480*512*4);
  float* sf1=(float*)alloc(1024*4); float* tf1=(float*)alloc(1024*4);
  float* f1_raw=(float*)alloc((size_t)480*1024*4);
  float* sf2=(float*)alloc(512*4); float* tf2=(float*)alloc(512*4);
  float* f2_raw=(float*)alloc((size_t)480*512*4);
  float* Op = (float*)alloc((size_t)8*64*64*128*4);
  float* Mp = (float*)alloc((size_t)8*64*64*4);
  float* Lp = (float*)alloc((size_t)8*64*64*4);
  ushort* Wdc_b = (ushort*)alloc((size_t)512*1024*2);
  ushort* Wkv_b = (ushort*)alloc((size_t)1536*512*2);
  ushort* y1 = (ushort*)alloc((size_t)73728*512*2);
  ushort* Kbuf = (ushort*)alloc((size_t)73728*512*2);
  ushort* Vt  = (ushort*)alloc((size_t)64*128*9216*2);
  ushort* At = (ushort*)alloc((size_t)73728*1024*2);

  init_kernel<<<1024,256,0,stream>>>(W_dc, W_kv, Wdc_b, Wkv_b, zero_base);
  transpose_kernel<<<dim3(144,16,8),256,0,stream>>>(im, At);
  gemm_bt<0><<<2304,256,0,stream>>>(At, Wdc_b, y1, nullptr, s1_sum, s1_sq, 4, 512, 1024);
  bn_finalize<<<2,256,0,stream>>>(s1_sum, s1_sq, g_dc, b_dc, sc1, sh1, 512, 1.f/73728.f);
  bn_hswish<<<2048,256,0,stream>>>(y1, sc1, sh1);
  gemm_bt<1><<<6912,256,0,stream>>>(y1, Wkv_b, Kbuf, Vt, s2_sum, s2_sq, 12, 1536, 512);
  bn_finalize<<<6,256,0,stream>>>(s2_sum, s2_sq, g_kv, b_kv, sc2, sh2, 1536, 1.f/73728.f);
  q_gemm<<<60,256,0,stream>>>(text, W_q, qraw);
  q_bn_qh<<<1,512,0,stream>>>(qraw, g_q, b_q, sc2, sh2, Qh, cQ);
  attn_flash<<<dim3(8,8,8),256,0,stream>>>(Qh, cQ, Kbuf, Vt, biases, Op, Mp, Lp);
  attn_combine<<<dim3(60,64),128,0,stream>>>(Op, Mp, Lp, attn_o);
  rowgemm8<1024,512,3><<<dim3(60,2),256,0,stream>>>(attn_o, W_proj, sc2, sh2, nullptr, nullptr, proj_raw, s3_sum, s3_sq);
  bn_finalize<<<2,256,0,stream>>>(s3_sum, s3_sq, g_proj, b_proj, sp, tp, 512, 1.f/480.f);
  rowgemm8<512,1024,4><<<dim3(60,4),256,0,stream>>>(proj_raw, W_f1, sp, tp, text, textd, f1_raw, s4_sum, s4_sq);
  bn_finalize<<<4,256,0,stream>>>(s4_sum, s4_sq, g_f1, b_f1, sf1, tf1, 1024, 1.f/480.f);
  rowgemm8<1024,512,2><<<dim3(60,2),256,0,stream>>>(f1_raw, W_f2, sf1, tf1, nullptr, nullptr, f2_raw, s5_sum, s5_sq);
  bn_finalize<<<2,256,0,stream>>>(s5_sum, s5_sq, g_f2, b_f2, sf2, tf2, 512, 1.f/480.f);
  final_out<<<120,256,0,stream>>>(f2_raw, sf2, tf2, textd, outp);
}